// Round 3
// baseline (1107.243 us; speedup 1.0000x reference)
//
#include <hip/hip_runtime.h>
#include <hip/hip_bf16.h>
#include <math.h>

// Problem dims (fixed)
constexpr int NB  = 8;    // batch
constexpr int NR  = 128;  // rule nodes
constexpr int HID = 256;  // hidden
constexpr int NIN = 512;  // input dim
constexpr int NHD = 4;    // heads
constexpr int DHD = 64;   // head dim
constexpr int NBLK = 256; // persistent workgroups (== CU count; LDS 45KB => >=3 blocks/CU capacity)
constexpr size_t SZ = (size_t)NB * NR * HID;  // 262144

struct KP {
    const float *x, *We, *be, *msg_W1, *msg_b1, *msg_W2, *msg_b2;
    const float *upd_W1, *upd_b1, *upd_W2, *upd_b2, *ln_g, *ln_b, *rule_adj;
    const float *Wq, *bq, *Wk, *bk, *Wv, *bv, *Wo, *bo, *ro_W1, *ro_b1, *ro_W2, *ro_b2;
    float* out;
    int*   bar;      // grid barrier counter (memset to 0 per launch)
    float *h, *bufA, *bufBB, *bufAgg, *bufP1, *bufU1, *bufU;
    float *W2u, *mb2u, *Aw, *rsum, *h0g, *c0g, *c1g, *scratch;
};

union LdsU {
    struct { float As[16][68]; float Bs[16][64]; } g;                       // gemm tile
    struct { float xs[NIN]; float v0[HID], v1[HID], v2[HID];
             float red[1024]; } hd;                                        // head/tail gemv
    struct { float KhT[64][128]; float S[16][128]; float qs[16][64]; } att; // attention
};

// ---------------------------------------------------------------------------
// Grid barrier: all NBLK blocks co-resident (grid == #CUs, modest resources).
// Monotonic phase counter; agent-scope fences for cross-XCD visibility.
// ---------------------------------------------------------------------------
__device__ __forceinline__ void gsync(int* bar, int ph) {
    __builtin_amdgcn_fence(__ATOMIC_RELEASE, "agent");
    __syncthreads();
    if (threadIdx.x == 0) {
        __hip_atomic_fetch_add(bar, 1, __ATOMIC_ACQ_REL, __HIP_MEMORY_SCOPE_AGENT);
        while (__hip_atomic_load(bar, __ATOMIC_ACQUIRE, __HIP_MEMORY_SCOPE_AGENT) < ph * NBLK)
            __builtin_amdgcn_s_sleep(2);
    }
    __syncthreads();
    __builtin_amdgcn_fence(__ATOMIC_ACQUIRE, "agent");
}

// ---------------------------------------------------------------------------
// Wave-split GEMV: y[0..255] = act(xs @ W + bias). W row-major [K,256].
// Wave w owns K/4 rows; lane l covers outputs 4l..4l+3. K in {256,512}.
// ---------------------------------------------------------------------------
__device__ __forceinline__ void gemv256(
    const float* xs, const float* __restrict__ W, int K,
    const float* __restrict__ bias, int relu, float* ys, float* red)
{
    int tid = threadIdx.x;
    int w = tid >> 6, l = tid & 63;
    int kpw = K >> 2;
    float4 acc = {0.f, 0.f, 0.f, 0.f};
    const float* Wp = W + (size_t)(w * kpw) * HID + l * 4;
    const float* xp = xs + w * kpw;
#pragma unroll 16
    for (int kk = 0; kk < kpw; ++kk) {
        float xv = xp[kk];
        float4 wv = *(const float4*)(Wp + (size_t)kk * HID);
        acc.x += xv * wv.x; acc.y += xv * wv.y;
        acc.z += xv * wv.z; acc.w += xv * wv.w;
    }
    *(float4*)&red[w * 256 + l * 4] = acc;
    __syncthreads();
    float v = red[tid] + red[256 + tid] + red[512 + tid] + red[768 + tid];
    if (bias) v += bias[tid];
    if (relu) v = fmaxf(v, 0.0f);
    ys[tid] = v;
    __syncthreads();
}

// ---------------------------------------------------------------------------
// 64x64-tile fp32 GEMM (K=256 fixed), register-double-buffered staging.
// A direct (row-major, ld=256) or implicit layer0-u1 (A==nullptr):
//   Arow(m,k) = relu(c0g[b,k] + rsum[i]*c1g[b,k] + ub1[k]),  b=m>>7, i=m&127
// epi: 0 none; 1 +bias[n]; 2 stageC: +P1[m,n] + rsum[i]*mb2u[n] + ub1[n], relu
// ---------------------------------------------------------------------------
__device__ __forceinline__ void gemm_tile(
    LdsU& L, int m0, int n0,
    const float* __restrict__ A, const float* __restrict__ B, float* __restrict__ C,
    int epi, const float* __restrict__ bias,
    const float* __restrict__ P1, const float* __restrict__ rsum,
    const float* __restrict__ mb2u, const float* __restrict__ ub1,
    const float* __restrict__ c0g, const float* __restrict__ c1g)
{
    int tid = threadIdx.x;
    int tx = tid & 15, ty = tid >> 4;
    int arow = tid >> 2, acol = (tid & 3) << 2;
    int brow = tid >> 4, bcol = (tid & 15) << 2;

    float rsw = 0.f;
    const float *c0b = nullptr, *c1b = nullptr;
    if (!A) {
        int m = m0 + arow;
        c0b = c0g + ((size_t)(m >> 7) << 8);
        c1b = c1g + ((size_t)(m >> 7) << 8);
        rsw = rsum[m & 127];
    }
    auto loadA = [&](int k0) -> float4 {
        if (A) return *(const float4*)&A[(size_t)(m0 + arow) * HID + k0 + acol];
        int kx = k0 + acol;
        float4 c0v = *(const float4*)(c0b + kx);
        float4 c1v = *(const float4*)(c1b + kx);
        float4 ubv = *(const float4*)(ub1 + kx);
        float4 r;
        r.x = fmaxf(c0v.x + rsw * c1v.x + ubv.x, 0.f);
        r.y = fmaxf(c0v.y + rsw * c1v.y + ubv.y, 0.f);
        r.z = fmaxf(c0v.z + rsw * c1v.z + ubv.z, 0.f);
        r.w = fmaxf(c0v.w + rsw * c1v.w + ubv.w, 0.f);
        return r;
    };

    float acc[4][4] = {};
    float4 av = loadA(0);
    float4 bv = *(const float4*)&B[(size_t)brow * HID + n0 + bcol];

    for (int k0 = 0; k0 < 256; k0 += 16) {
        L.g.As[acol + 0][arow] = av.x;
        L.g.As[acol + 1][arow] = av.y;
        L.g.As[acol + 2][arow] = av.z;
        L.g.As[acol + 3][arow] = av.w;
        *(float4*)&L.g.Bs[brow][bcol] = bv;
        __syncthreads();
        float4 avn = av, bvn = bv;
        if (k0 + 16 < 256) {
            avn = loadA(k0 + 16);
            bvn = *(const float4*)&B[(size_t)(k0 + 16 + brow) * HID + n0 + bcol];
        }
#pragma unroll
        for (int kk = 0; kk < 16; ++kk) {
            float4 af = *(const float4*)&L.g.As[kk][ty << 2];
            float4 bf = *(const float4*)&L.g.Bs[kk][tx << 2];
            float a_[4] = {af.x, af.y, af.z, af.w};
            float b_[4] = {bf.x, bf.y, bf.z, bf.w};
#pragma unroll
            for (int i = 0; i < 4; ++i)
#pragma unroll
                for (int j = 0; j < 4; ++j) acc[i][j] += a_[i] * b_[j];
        }
        __syncthreads();
        av = avn; bv = bvn;
    }

#pragma unroll
    for (int i = 0; i < 4; ++i) {
        int m = m0 + (ty << 2) + i;
        int n = n0 + (tx << 2);
        float v[4] = {acc[i][0], acc[i][1], acc[i][2], acc[i][3]};
        if (epi == 1) {
            float4 bb = *(const float4*)(bias + n);
            v[0] += bb.x; v[1] += bb.y; v[2] += bb.z; v[3] += bb.w;
        } else if (epi == 2) {
            float4 pv = *(const float4*)&P1[(size_t)m * HID + n];
            float rs = rsum[m & 127];
            float4 mv = *(const float4*)(mb2u + n);
            float4 uv = *(const float4*)(ub1 + n);
            v[0] = fmaxf(v[0] + pv.x + rs * mv.x + uv.x, 0.f);
            v[1] = fmaxf(v[1] + pv.y + rs * mv.y + uv.y, 0.f);
            v[2] = fmaxf(v[2] + pv.z + rs * mv.z + uv.z, 0.f);
            v[3] = fmaxf(v[3] + pv.w + rs * mv.w + uv.w, 0.f);
        }
        float4 o = {v[0], v[1], v[2], v[3]};
        *(float4*)&C[(size_t)m * HID + n] = o;
    }
}

// ---------------------------------------------------------------------------
// LayerNorm over 1024 rows: one wave per row (4 rows/block).
// bcast=1: src row = hsrc[b]; else src row = hsrc[row]. h[row] = LN(src+u)*g+b
// ---------------------------------------------------------------------------
__device__ __forceinline__ void ln_stage(
    float* __restrict__ h, const float* __restrict__ hsrc, int bcast,
    const float* __restrict__ u, const float* __restrict__ g, const float* __restrict__ bt)
{
    int w = threadIdx.x >> 6, l = threadIdx.x & 63;
    int row = blockIdx.x * 4 + w;
    const float* hr = bcast ? (hsrc + ((size_t)(row >> 7)) * HID) : (hsrc + (size_t)row * HID);
    float4 hv = *(const float4*)(hr + l * 4);
    float4 uv = *(const float4*)(u + (size_t)row * HID + l * 4);
    float v0 = hv.x + uv.x, v1 = hv.y + uv.y, v2 = hv.z + uv.z, v3 = hv.w + uv.w;
    float s = v0 + v1 + v2 + v3;
#pragma unroll
    for (int off = 32; off; off >>= 1) s += __shfl_xor(s, off);
    float mu = s * (1.0f / HID);
    float d0 = v0 - mu, d1 = v1 - mu, d2 = v2 - mu, d3 = v3 - mu;
    float s2 = d0 * d0 + d1 * d1 + d2 * d2 + d3 * d3;
#pragma unroll
    for (int off = 32; off; off >>= 1) s2 += __shfl_xor(s2, off);
    float inv = rsqrtf(s2 * (1.0f / HID) + 1e-5f);
    float4 gv = *(const float4*)(g + l * 4);
    float4 bv = *(const float4*)(bt + l * 4);
    float4 o = {d0 * inv * gv.x + bv.x, d1 * inv * gv.y + bv.y,
                d2 * inv * gv.z + bv.z, d3 * inv * gv.w + bv.w};
    *(float4*)&h[(size_t)row * HID + l * 4] = o;
}

// ---------------------------------------------------------------------------
// Head (layer-0 collapse), one block per batch.
// ---------------------------------------------------------------------------
__device__ void head_fn(LdsU& L, const KP& P, int b) {
    int t = threadIdx.x;
    float* xs  = L.hd.xs;
    float* red = L.hd.red;
    xs[t]       = P.x[b * NIN + t];
    xs[256 + t] = P.x[b * NIN + 256 + t];
    __syncthreads();
    gemv256(xs, P.We, NIN, P.be, 0, L.hd.v0, red);           // h0
    xs[t] = L.hd.v0[t]; xs[256 + t] = L.hd.v0[t];
    __syncthreads();
    gemv256(xs, P.msg_W1, NIN, P.msg_b1, 1, L.hd.v1, red);   // p0
    gemv256(L.hd.v1, P.msg_W2, HID, P.msg_b2, 0, L.hd.v2, red); // m0
    float h0v = L.hd.v0[t];
    float m0v = L.hd.v2[t];
    __syncthreads();
    gemv256(L.hd.v0, P.upd_W1, HID, nullptr, 0, L.hd.v1, red);                          // c0
    float c0v = L.hd.v1[t];
    __syncthreads();
    gemv256(L.hd.v2, P.upd_W1 + (size_t)HID * HID, HID, nullptr, 0, L.hd.v1, red);      // c1
    P.h0g[b * HID + t] = h0v;
    P.c0g[b * HID + t] = c0v;
    P.c1g[b * HID + t] = L.hd.v1[t];
    (void)m0v;
}

// ---------------------------------------------------------------------------
// Tail, one block per batch: g=mean_i pooled; @Wo+bo; relu(@roW1+rob1);
// @roW2+rob2; softmax -> out
// ---------------------------------------------------------------------------
__device__ void tail_fn(LdsU& L, const KP& P, int b) {
    int t = threadIdx.x;
    int w = t >> 6, l = t & 63;
    float* red = L.hd.red;
    {   // mean over 128 rows
        float4 acc = {0.f, 0.f, 0.f, 0.f};
        const float* pb = &P.bufP1[((size_t)b * NR + w * 32) * HID + l * 4];
#pragma unroll 8
        for (int ii = 0; ii < 32; ++ii) {
            float4 pv = *(const float4*)(pb + (size_t)ii * HID);
            acc.x += pv.x; acc.y += pv.y; acc.z += pv.z; acc.w += pv.w;
        }
        *(float4*)&red[w * 256 + l * 4] = acc;
        __syncthreads();
        L.hd.v0[t] = (red[t] + red[256 + t] + red[512 + t] + red[768 + t]) * (1.0f / NR);
        __syncthreads();
    }
    gemv256(L.hd.v0, P.Wo, HID, P.bo, 0, L.hd.v1, red);
    gemv256(L.hd.v1, P.ro_W1, HID, P.ro_b1, 1, L.hd.v2, red);
    {   // logits: N=128; lane l -> 2 outputs; wave w -> K quarter
        float2 acc = {0.f, 0.f};
        const float* Wp = P.ro_W2 + (size_t)(w * 64) * NR + l * 2;
        const float* xp = L.hd.v2 + w * 64;
#pragma unroll 8
        for (int kk = 0; kk < 64; ++kk) {
            float xv = xp[kk];
            float2 wv = *(const float2*)(Wp + (size_t)kk * NR);
            acc.x += xv * wv.x; acc.y += xv * wv.y;
        }
        *(float2*)&red[w * 128 + l * 2] = acc;
        __syncthreads();
    }
    float logit = -1e30f;
    if (t < NR) logit = red[t] + red[128 + t] + red[256 + t] + red[384 + t] + P.ro_b2[t];
    __syncthreads();
    float m = logit;
#pragma unroll
    for (int off = 32; off; off >>= 1) m = fmaxf(m, __shfl_xor(m, off));
    if (l == 0) red[w] = m;
    __syncthreads();
    m = fmaxf(red[0], red[1]);
    float e = (t < NR) ? expf(logit - m) : 0.0f;
    float ssum = e;
#pragma unroll
    for (int off = 32; off; off >>= 1) ssum += __shfl_xor(ssum, off);
    if (l == 0) red[4 + w] = ssum;
    __syncthreads();
    float tot = red[4] + red[5];
    if (t < NR) P.out[b * NR + t] = e / tot;
}

// ---------------------------------------------------------------------------
// Aggregate: aggpre[b,i,h] = sum_j Aw[i,j]*relu(a[b,i,h]+bb[b,j,h]+mb1[h])
// block: b=blk>>5, i0=(blk&31)*4
// ---------------------------------------------------------------------------
__device__ void aggregate_fn(const KP& P, const float* __restrict__ mb1, int blk) {
    int b  = blk >> 5;
    int i0 = (blk & 31) * 4;
    int hh = threadIdx.x;
    float bias = mb1[hh];
    float ai[4], acc[4] = {0.f, 0.f, 0.f, 0.f};
#pragma unroll
    for (int ii = 0; ii < 4; ++ii)
        ai[ii] = P.bufA[((size_t)b * NR + i0 + ii) * HID + hh] + bias;
    const float* bbb = &P.bufBB[(size_t)b * NR * HID + hh];
#pragma unroll 2
    for (int j = 0; j < NR; ++j) {
        float bj = bbb[(size_t)j * HID];
#pragma unroll
        for (int ii = 0; ii < 4; ++ii) {
            float pre = fmaxf(ai[ii] + bj, 0.0f);
            acc[ii] += P.Aw[(i0 + ii) * NR + j] * pre;
        }
    }
#pragma unroll
    for (int ii = 0; ii < 4; ++ii)
        P.bufAgg[((size_t)b * NR + i0 + ii) * HID + hh] = acc[ii];
}

// ---------------------------------------------------------------------------
// Fused attention stage: blk = bh*8 + ig; i-tile of 16 rows, one (b,head).
// ---------------------------------------------------------------------------
__device__ void attention_fn(LdsU& L, const KP& P, int blk) {
    int bh = blk >> 3, ig = blk & 7;
    int b = bh >> 2, hd = bh & 3;
    int i0 = ig * 16;
    int t = threadIdx.x;
    const float* qg = P.bufA   + ((size_t)b * NR) * HID + hd * DHD;
    const float* kg = P.bufBB  + ((size_t)b * NR) * HID + hd * DHD;
    const float* vg = P.bufAgg + ((size_t)b * NR) * HID + hd * DHD;

    {   // stage K^T into LDS: KhT[d][j]
        int j = t >> 1, half = t & 1;
        const float* krow = kg + (size_t)j * HID + half * 32;
#pragma unroll
        for (int c = 0; c < 32; c += 4) {
            float4 kv = *(const float4*)(krow + c);
            L.att.KhT[half * 32 + c + 0][j] = kv.x;
            L.att.KhT[half * 32 + c + 1][j] = kv.y;
            L.att.KhT[half * 32 + c + 2][j] = kv.z;
            L.att.KhT[half * 32 + c + 3][j] = kv.w;
        }
    }
    {   // stage q rows
        int ii = t >> 4, d0 = (t & 15) * 4;
        *(float4*)&L.att.qs[ii][d0] = *(const float4*)(qg + (size_t)(i0 + ii) * HID + d0);
    }
    __syncthreads();
    {   // scores: thread handles 8 i x its j
        int j = t & 127, ii2 = t >> 7;
        float acc[8] = {0.f,0.f,0.f,0.f,0.f,0.f,0.f,0.f};
#pragma unroll 4
        for (int d = 0; d < 64; ++d) {
            float kv = L.att.KhT[d][j];
#pragma unroll
            for (int ii = 0; ii < 8; ++ii) acc[ii] += L.att.qs[ii2 * 8 + ii][d] * kv;
        }
#pragma unroll
        for (int ii = 0; ii < 8; ++ii) L.att.S[ii2 * 8 + ii][j] = acc[ii] * 0.125f;
    }
    __syncthreads();
    {   // softmax: wave w rows 4w..4w+3; lane covers j=l, l+64
        int w = t >> 6, l = t & 63;
#pragma unroll
        for (int r = w * 4; r < w * 4 + 4; ++r) {
            float e0 = L.att.S[r][l], e1 = L.att.S[r][l + 64];
            float mx = fmaxf(e0, e1);
#pragma unroll
            for (int off = 32; off; off >>= 1) mx = fmaxf(mx, __shfl_xor(mx, off));
            e0 = expf(e0 - mx); e1 = expf(e1 - mx);
            float sm = e0 + e1;
#pragma unroll
            for (int off = 32; off; off >>= 1) sm += __shfl_xor(sm, off);
            float inv = 1.0f / sm;
            L.att.S[r][l] = e0 * inv; L.att.S[r][l + 64] = e1 * inv;
        }
    }
    __syncthreads();
    {   // PV: thread (d=t&63, ir=t>>6); v read from global (L2-hot)
        int d = t & 63, ir = t >> 6;
        float accv[4] = {0.f, 0.f, 0.f, 0.f};
        const float* vp = vg + d;
#pragma unroll 8
        for (int j = 0; j < NR; ++j) {
            float vv = vp[(size_t)j * HID];
#pragma unroll
            for (int p = 0; p < 4; ++p) accv[p] += L.att.S[p * 4 + ir][j] * vv;
        }
#pragma unroll
        for (int p = 0; p < 4; ++p)
            P.bufP1[((size_t)(b * NR + i0 + p * 4 + ir)) * HID + hd * DHD + d] = accv[p];
    }
}

// ---------------------------------------------------------------------------
// Weight prefetch (stage 0 idle blocks): stream all weights to warm L2/L3.
// ---------------------------------------------------------------------------
__device__ void prefetch_fn(const KP& P, int pfid, int npf) {
    const float* arr[11] = {P.We, P.msg_W1, P.msg_W2, P.upd_W1, P.upd_W2,
                            P.Wq, P.Wk, P.Wv, P.Wo, P.ro_W1, P.ro_W2};
    const int n4[11] = {32768, 98304, 49152, 98304, 49152,
                        16384, 16384, 16384, 16384, 16384, 8192};
    float s = 0.f;
    int t = threadIdx.x;
    for (int a = 0; a < 11; ++a) {
        const float4* p4 = (const float4*)arr[a];
        for (int i = pfid * 256 + t; i < n4[a]; i += npf * 256) {
            float4 v = p4[i];
            s += v.x + v.y + v.z + v.w;
        }
    }
    if (s == 1.0e37f) P.scratch[pfid] = s;  // never true; keeps loads live
}

// ---------------------------------------------------------------------------
__global__ __launch_bounds__(256, 2) void mega_kernel(KP P) {
    __shared__ LdsU L;
    int blk = blockIdx.x;
    int t = threadIdx.x;
    int ph = 0;

    // ======== stage 0: head | W2u precompute | mb2u | adjacency | prefetch ====
    if (blk < 8) {
        head_fn(L, P, blk);
    } else if (blk < 40) {
        int idx = blk - 8, l2 = idx >> 4, t16 = idx & 15;
        gemm_tile(L, (t16 >> 2) * 64, (t16 & 3) * 64,
                  P.msg_W2 + (size_t)(1 + l2) * HID * HID,
                  P.upd_W1 + (size_t)(1 + l2) * 2 * HID * HID + (size_t)HID * HID,
                  P.W2u + (size_t)l2 * HID * HID,
                  0, nullptr, nullptr, nullptr, nullptr, nullptr, nullptr, nullptr);
    } else if (blk < 42) {
        int l2 = blk - 40;
        const float* b2v = P.msg_b2 + (1 + l2) * HID;
        const float* Bm = P.upd_W1 + (size_t)(1 + l2) * 2 * HID * HID + (size_t)HID * HID;
        float acc = 0.f;
#pragma unroll 4
        for (int k = 0; k < HID; ++k) acc += b2v[k] * Bm[(size_t)k * HID + t];
        P.mb2u[l2 * HID + t] = acc;
    } else if (blk < 74) {
        int rr = (blk - 42) * 4 + (t >> 6);
        int l = t & 63;
        float s_loc = 0.f;
#pragma unroll
        for (int rep = 0; rep < 2; ++rep) {
            int j = l + rep * 64;
            float xv = P.rule_adj[rr * NR + j];
            float sg = 1.0f / (1.0f + expf(-xv));
            if (j == rr) sg = 0.0f;
            P.Aw[rr * NR + j] = sg;
            s_loc += sg;
        }
#pragma unroll
        for (int off = 32; off; off >>= 1) s_loc += __shfl_xor(s_loc, off);
        if (l == 0) P.rsum[rr] = s_loc;
    } else {
        prefetch_fn(P, blk - 74, NBLK - 74);
    }
    gsync(P.bar, ++ph);

    // ======== stage 1: layer0  u = u1_implicit @ uW2 + ub2 ====================
    if (blk < 64) {
        gemm_tile(L, (blk >> 2) * 64, (blk & 3) * 64,
                  nullptr, P.upd_W2, P.bufU,
                  1, P.upd_b2,
                  nullptr, P.rsum, nullptr, P.upd_b1, P.c0g, P.c1g);
    }
    gsync(P.bar, ++ph);

    // ======== stage 2: h = LN(h0 + u) =========================================
    ln_stage(P.h, P.h0g, 1, P.bufU, P.ln_g, P.ln_b);
    gsync(P.bar, ++ph);

    // ======== layers 1..2 =====================================================
    for (int l = 1; l < 3; ++l) {
        const float* mW1 = P.msg_W1 + (size_t)l * 2 * HID * HID;
        const float* mb1 = P.msg_b1 + (size_t)l * HID;
        const float* uW1 = P.upd_W1 + (size_t)l * 2 * HID * HID;
        const float* ub1 = P.upd_b1 + (size_t)l * HID;
        const float* uW2 = P.upd_W2 + (size_t)l * HID * HID;
        const float* ub2 = P.upd_b2 + (size_t)l * HID;

        // A: a = h@W1a ; bb = h@W1b ; P1 = h@uW1a
        if (blk < 192) {
            int z = blk >> 6, tile = blk & 63;
            const float* B = (z == 0) ? mW1 : (z == 1) ? (mW1 + (size_t)HID * HID) : uW1;
            float* C = (z == 0) ? P.bufA : (z == 1) ? P.bufBB : P.bufP1;
            gemm_tile(L, (tile >> 2) * 64, (tile & 3) * 64, P.h, B, C,
                      0, nullptr, nullptr, nullptr, nullptr, nullptr, nullptr, nullptr);
        }
        gsync(P.bar, ++ph);

        // B: aggregate
        aggregate_fn(P, mb1, blk);
        gsync(P.bar, ++ph);

        // C: u1 = relu(aggpre@W2u + P1 + rsum[i]*mb2u + ub1)
        if (blk < 64) {
            gemm_tile(L, (blk >> 2) * 64, (blk & 3) * 64,
                      P.bufAgg, P.W2u + (size_t)(l - 1) * HID * HID, P.bufU1,
                      2, nullptr,
                      P.bufP1, P.rsum, P.mb2u + (l - 1) * HID, ub1, nullptr, nullptr);
        }
        gsync(P.bar, ++ph);

        // D: u = u1@uW2 + ub2
        if (blk < 64) {
            gemm_tile(L, (blk >> 2) * 64, (blk & 3) * 64,
                      P.bufU1, uW2, P.bufU,
                      1, ub2, nullptr, nullptr, nullptr, nullptr, nullptr, nullptr);
        }
        gsync(P.bar, ++ph);

        // E: h = LN(h + u)
        ln_stage(P.h, P.h, 0, P.bufU, P.ln_g + (size_t)l * HID, P.ln_b + (size_t)l * HID);
        gsync(P.bar, ++ph);
    }

    // ======== qkv =============================================================
    if (blk < 192) {
        int z = blk >> 6, tile = blk & 63;
        const float* B = (z == 0) ? P.Wq : (z == 1) ? P.Wk : P.Wv;
        const float* bias = (z == 0) ? P.bq : (z == 1) ? P.bk : P.bv;
        float* C = (z == 0) ? P.bufA : (z == 1) ? P.bufBB : P.bufAgg;
        gemm_tile(L, (tile >> 2) * 64, (tile & 3) * 64, P.h, B, C,
                  1, bias, nullptr, nullptr, nullptr, nullptr, nullptr, nullptr);
    }
    gsync(P.bar, ++ph);

    // ======== attention (score+softmax+PV) -> pooled (bufP1) ==================
    attention_fn(L, P, blk);
    gsync(P.bar, ++ph);

    // ======== tail ============================================================
    if (blk < 8) tail_fn(L, P, blk);
}

// ---------------------------------------------------------------------------
extern "C" void kernel_launch(void* const* d_in, const int* in_sizes, int n_in,
                              void* d_out, int out_size, void* d_ws, size_t ws_size,
                              hipStream_t stream)
{
    KP P;
    P.x        = (const float*)d_in[0];
    P.We       = (const float*)d_in[1];
    P.be       = (const float*)d_in[2];
    P.msg_W1   = (const float*)d_in[3];
    P.msg_b1   = (const float*)d_in[4];
    P.msg_W2   = (const float*)d_in[5];
    P.msg_b2   = (const float*)d_in[6];
    P.upd_W1   = (const float*)d_in[7];
    P.upd_b1   = (const float*)d_in[8];
    P.upd_W2   = (const float*)d_in[9];
    P.upd_b2   = (const float*)d_in[10];
    P.ln_g     = (const float*)d_in[11];
    P.ln_b     = (const float*)d_in[12];
    P.rule_adj = (const float*)d_in[13];
    P.Wq       = (const float*)d_in[14];
    P.bq       = (const float*)d_in[15];
    P.Wk       = (const float*)d_in[16];
    P.bk       = (const float*)d_in[17];
    P.Wv       = (const float*)d_in[18];
    P.bv       = (const float*)d_in[19];
    P.Wo       = (const float*)d_in[20];
    P.bo       = (const float*)d_in[21];
    P.ro_W1    = (const float*)d_in[22];
    P.ro_b1    = (const float*)d_in[23];
    P.ro_W2    = (const float*)d_in[24];
    P.ro_b2    = (const float*)d_in[25];
    P.out      = (float*)d_out;

    float* f  = (float*)d_ws;
    P.bar     = (int*)f;            // 64 floats reserved
    float* b0 = f + 64;
    P.h      = b0;            b0 += SZ;
    P.bufA   = b0;            b0 += SZ;
    P.bufBB  = b0;            b0 += SZ;
    P.bufAgg = b0;            b0 += SZ;
    P.bufP1  = b0;            b0 += SZ;
    P.bufU1  = b0;            b0 += SZ;
    P.bufU   = b0;            b0 += SZ;
    P.W2u    = b0;            b0 += 2 * HID * HID;
    P.mb2u   = b0;            b0 += 2 * HID;
    P.Aw     = b0;            b0 += NR * NR;
    P.rsum   = b0;            b0 += NR;
    P.h0g    = b0;            b0 += NB * HID;
    P.c0g    = b0;            b0 += NB * HID;
    P.c1g    = b0;            b0 += NB * HID;
    P.scratch= b0;            b0 += NBLK;

    hipMemsetAsync(d_ws, 0, 256, stream);  // zero the barrier counter
    hipLaunchKernelGGL(mega_kernel, dim3(NBLK), dim3(256), 0, stream, P);
}

// Round 4
// 310.434 us; speedup vs baseline: 3.5668x; 3.5668x over previous
//
#include <hip/hip_runtime.h>
#include <math.h>

// Problem dims (fixed)
constexpr int NB  = 8;    // batch
constexpr int NR  = 128;  // rule nodes
constexpr int HID = 256;  // hidden
constexpr int NIN = 512;  // input dim
constexpr int DHD = 64;   // head dim
constexpr size_t SZ = (size_t)NB * NR * HID;  // 262144

struct KP {
    const float *x, *We, *be, *msg_W1, *msg_b1, *msg_W2, *msg_b2;
    const float *upd_W1, *upd_b1, *upd_W2, *upd_b2, *ln_g, *ln_b, *rule_adj;
    const float *Wq, *bq, *Wk, *bk, *Wv, *bv, *Wo, *bo, *ro_W1, *ro_b1, *ro_W2, *ro_b2;
    float* out;
    float *hu0, *hu1, *hu2;          // raw residual streams (pre-LN)
    float *bufA, *bufBB, *bufP1, *bufU1;
    float *W2u, *mb2u, *Aw, *rsum, *h0g, *c0g, *c1g;
    float *sts;                      // [3][2][1024] stats: sum, sumsq per layer
    float *scratch;
};

struct HdLds { float xs[NIN]; float v0[HID], v1[HID], v2[HID]; float red[1024]; };

// ---------------------------------------------------------------------------
// Wave-split GEMV: y[0..255] = act(xs @ W + bias). W row-major [K,256].
// ---------------------------------------------------------------------------
__device__ __forceinline__ void gemv256(
    const float* xs, const float* __restrict__ W, int K,
    const float* __restrict__ bias, int relu, float* ys, float* red)
{
    int tid = threadIdx.x;
    int w = tid >> 6, l = tid & 63;
    int kpw = K >> 2;
    float4 acc = {0.f, 0.f, 0.f, 0.f};
    const float* Wp = W + (size_t)(w * kpw) * HID + l * 4;
    const float* xp = xs + w * kpw;
#pragma unroll 16
    for (int kk = 0; kk < kpw; ++kk) {
        float xv = xp[kk];
        float4 wv = *(const float4*)(Wp + (size_t)kk * HID);
        acc.x += xv * wv.x; acc.y += xv * wv.y;
        acc.z += xv * wv.z; acc.w += xv * wv.w;
    }
    *(float4*)&red[w * 256 + l * 4] = acc;
    __syncthreads();
    float v = red[tid] + red[256 + tid] + red[512 + tid] + red[768 + tid];
    if (bias) v += bias[tid];
    if (relu) v = fmaxf(v, 0.0f);
    ys[tid] = v;
    __syncthreads();
}

// ---------------------------------------------------------------------------
// 64x64-tile fp32 GEMM core (K=256), register-double-buffered staging.
//  A != null: raw A [*,256]; if ssum != null apply LN-on-load with stats+g/b.
//  A == null: implicit layer0 A: relu(c0g[b,k] + rsum[i]*c1g[b,k] + ub1[k])
// ---------------------------------------------------------------------------
__device__ __forceinline__ void gemm_core(
    float (&As)[16][68], float (&Bs)[16][64], int m0, int n0,
    const float* __restrict__ A,
    const float* __restrict__ ssum, const float* __restrict__ ssq,
    const float* __restrict__ lng, const float* __restrict__ lnb,
    const float* __restrict__ B,
    const float* __restrict__ c0g, const float* __restrict__ c1g,
    const float* __restrict__ rsum, const float* __restrict__ ub1,
    float (&acc)[4][4])
{
    int tid = threadIdx.x;
    int ty = tid >> 4, tx = tid & 15;
    int arow = tid >> 2, acol = (tid & 3) << 2;
    int brow = tid >> 4, bcol = (tid & 15) << 2;
    int m = m0 + arow;

    bool imp = (A == nullptr);
    bool ln  = (ssum != nullptr);
    float mu = 0.f, inv = 1.f, rsw = 0.f;
    const float *c0b = nullptr, *c1b = nullptr;
    if (imp) {
        c0b = c0g + ((size_t)(m >> 7) << 8);
        c1b = c1g + ((size_t)(m >> 7) << 8);
        rsw = rsum[m & 127];
    } else if (ln) {
        float s = ssum[m], q = ssq[m];
        mu = s * (1.0f / HID);
        inv = rsqrtf(q * (1.0f / HID) - mu * mu + 1e-5f);
    }

    auto loadA = [&](int k0) -> float4 {
        int kx = k0 + acol;
        if (imp) {
            float4 c0v = *(const float4*)(c0b + kx);
            float4 c1v = *(const float4*)(c1b + kx);
            float4 ub  = *(const float4*)(ub1 + kx);
            float4 r;
            r.x = fmaxf(c0v.x + rsw * c1v.x + ub.x, 0.f);
            r.y = fmaxf(c0v.y + rsw * c1v.y + ub.y, 0.f);
            r.z = fmaxf(c0v.z + rsw * c1v.z + ub.z, 0.f);
            r.w = fmaxf(c0v.w + rsw * c1v.w + ub.w, 0.f);
            return r;
        }
        float4 v = *(const float4*)&A[(size_t)m * HID + kx];
        if (ln) {
            float4 g = *(const float4*)(lng + kx);
            float4 b = *(const float4*)(lnb + kx);
            v.x = (v.x - mu) * inv * g.x + b.x;
            v.y = (v.y - mu) * inv * g.y + b.y;
            v.z = (v.z - mu) * inv * g.z + b.z;
            v.w = (v.w - mu) * inv * g.w + b.w;
        }
        return v;
    };

    float4 av = loadA(0);
    float4 bv = *(const float4*)&B[(size_t)brow * HID + n0 + bcol];

    for (int k0 = 0; k0 < HID; k0 += 16) {
        As[acol + 0][arow] = av.x;
        As[acol + 1][arow] = av.y;
        As[acol + 2][arow] = av.z;
        As[acol + 3][arow] = av.w;
        *(float4*)&Bs[brow][bcol] = bv;
        __syncthreads();
        float4 avn = av, bvn = bv;
        if (k0 + 16 < HID) {
            avn = loadA(k0 + 16);
            bvn = *(const float4*)&B[(size_t)(k0 + 16 + brow) * HID + n0 + bcol];
        }
#pragma unroll
        for (int kk = 0; kk < 16; ++kk) {
            float4 af = *(const float4*)&As[kk][ty << 2];
            float4 bf = *(const float4*)&Bs[kk][tx << 2];
            float a_[4] = {af.x, af.y, af.z, af.w};
            float b_[4] = {bf.x, bf.y, bf.z, bf.w};
#pragma unroll
            for (int i = 0; i < 4; ++i)
#pragma unroll
                for (int j = 0; j < 4; ++j) acc[i][j] += a_[i] * b_[j];
        }
        __syncthreads();
        av = avn; bv = bvn;
    }
}

// Per-row stats accumulation: reduce (sum,sumsq) of 4 values across the 16
// tx-lanes sharing this row, then one atomicAdd pair per row per block.
__device__ __forceinline__ void stats_acc(
    float* __restrict__ ssum, float* __restrict__ ssq, int m, const float v[4])
{
    float s = v[0] + v[1] + v[2] + v[3];
    float q = v[0] * v[0] + v[1] * v[1] + v[2] * v[2] + v[3] * v[3];
#pragma unroll
    for (int off = 1; off < 16; off <<= 1) {
        s += __shfl_xor(s, off);
        q += __shfl_xor(q, off);
    }
    if ((threadIdx.x & 15) == 0) {
        atomicAdd(&ssum[m], s);
        atomicAdd(&ssq[m], q);
    }
}

// ---------------------------------------------------------------------------
// Head (layer-0 collapse), one block per batch: h0, then c0 = h0@uW1a,
// c1 = m0@uW1b where m0 = msg-MLP(h0 pair).
// ---------------------------------------------------------------------------
__device__ void head_fn(HdLds& L, const KP& P, int b) {
    int t = threadIdx.x;
    float* xs  = L.xs;
    float* red = L.red;
    xs[t]       = P.x[b * NIN + t];
    xs[256 + t] = P.x[b * NIN + 256 + t];
    __syncthreads();
    gemv256(xs, P.We, NIN, P.be, 0, L.v0, red);                 // h0
    xs[t] = L.v0[t]; xs[256 + t] = L.v0[t];
    __syncthreads();
    gemv256(xs, P.msg_W1, NIN, P.msg_b1, 1, L.v1, red);         // p0
    gemv256(L.v1, P.msg_W2, HID, P.msg_b2, 0, L.v2, red);       // m0
    float h0v = L.v0[t];
    __syncthreads();
    gemv256(L.v0, P.upd_W1, HID, nullptr, 0, L.v1, red);        // c0
    float c0v = L.v1[t];
    __syncthreads();
    gemv256(L.v2, P.upd_W1 + (size_t)HID * HID, HID, nullptr, 0, L.v1, red);  // c1
    P.h0g[b * HID + t] = h0v;
    P.c0g[b * HID + t] = c0v;
    P.c1g[b * HID + t] = L.v1[t];
}

// ---------------------------------------------------------------------------
// Setup: head | W2u = mW2[l]@uW1b[l] | mb2u | stats-zero | adjacency | prefetch
// ---------------------------------------------------------------------------
__global__ __launch_bounds__(256) void setup_kernel(KP P) {
    __shared__ union { struct { float As[16][68]; float Bs[16][64]; } g; HdLds hd; } L;
    int blk = blockIdx.x;
    int t = threadIdx.x;

    if (blk < 8) {
        head_fn(L.hd, P, blk);
    } else if (blk < 40) {
        int idx = blk - 8, l2 = idx >> 4, t16 = idx & 15;
        int m0 = (t16 >> 2) * 64, n0 = (t16 & 3) * 64;
        float acc[4][4] = {};
        gemm_core(L.g.As, L.g.Bs, m0, n0,
                  P.msg_W2 + (size_t)(1 + l2) * HID * HID,
                  nullptr, nullptr, nullptr, nullptr,
                  P.upd_W1 + (size_t)(1 + l2) * 2 * HID * HID + (size_t)HID * HID,
                  nullptr, nullptr, nullptr, nullptr, acc);
        int ty = t >> 4, tx = t & 15;
        float* C = P.W2u + (size_t)l2 * HID * HID;
#pragma unroll
        for (int i = 0; i < 4; ++i) {
            int m = m0 + (ty << 2) + i, n = n0 + (tx << 2);
            float4 o = {acc[i][0], acc[i][1], acc[i][2], acc[i][3]};
            *(float4*)&C[(size_t)m * HID + n] = o;
        }
    } else if (blk < 42) {
        int l2 = blk - 40;
        const float* b2v = P.msg_b2 + (1 + l2) * HID;
        const float* Bm = P.upd_W1 + (size_t)(1 + l2) * 2 * HID * HID + (size_t)HID * HID;
        float acc = 0.f;
#pragma unroll 4
        for (int k = 0; k < HID; ++k) acc += b2v[k] * Bm[(size_t)k * HID + t];
        P.mb2u[l2 * HID + t] = acc;
    } else if (blk < 44) {
        // zero stats: 3 layers x 2 x 1024 = 6144 floats
        int base = (blk - 42) * 3072;
        for (int i = t; i < 3072; i += 256) P.sts[base + i] = 0.f;
    } else if (blk < 76) {
        int rr = (blk - 44) * 4 + (t >> 6);
        int l = t & 63;
        float s_loc = 0.f;
#pragma unroll
        for (int rep = 0; rep < 2; ++rep) {
            int j = l + rep * 64;
            float xv = P.rule_adj[rr * NR + j];
            float sg = 1.0f / (1.0f + expf(-xv));
            if (j == rr) sg = 0.0f;
            P.Aw[rr * NR + j] = sg;
            s_loc += sg;
        }
#pragma unroll
        for (int off = 32; off; off >>= 1) s_loc += __shfl_xor(s_loc, off);
        if (l == 0) P.rsum[rr] = s_loc;
    } else {
        // prefetch all weights -> warm L3 (poison evicted it)
        int pfid = blk - 76, npf = 256 - 76;
        const float* arr[11] = {P.We, P.msg_W1, P.msg_W2, P.upd_W1, P.upd_W2,
                                P.Wq, P.Wk, P.Wv, P.Wo, P.ro_W1, P.ro_W2};
        const int n4[11] = {32768, 98304, 49152, 98304, 49152,
                            16384, 16384, 16384, 16384, 16384, 8192};
        float s = 0.f;
        for (int a = 0; a < 11; ++a) {
            const float4* p4 = (const float4*)arr[a];
            for (int i = pfid * 256 + t; i < n4[a]; i += npf * 256) {
                float4 v = p4[i];
                s += v.x + v.y + v.z + v.w;
            }
        }
        if (s == 1.0e37f) P.scratch[pfid] = s;  // never true; keeps loads live
    }
}

// ---------------------------------------------------------------------------
// Layer 0: hu0 = h0_bcast + (u1_implicit @ uW2 + ub2); accumulate stats0.
// ---------------------------------------------------------------------------
__global__ __launch_bounds__(256) void layer0_kernel(KP P) {
    __shared__ float As[16][68];
    __shared__ float Bs[16][64];
    int blk = blockIdx.x;
    int m0 = (blk >> 2) * 64, n0 = (blk & 3) * 64;
    float acc[4][4] = {};
    gemm_core(As, Bs, m0, n0,
              nullptr, nullptr, nullptr, nullptr, nullptr,
              P.upd_W2,
              P.c0g, P.c1g, P.rsum, P.upd_b1, acc);
    int t = threadIdx.x, ty = t >> 4, tx = t & 15;
    int b = m0 >> 7;
    float* s0 = P.sts, *q0 = P.sts + 1024;
#pragma unroll
    for (int i = 0; i < 4; ++i) {
        int m = m0 + (ty << 2) + i, n = n0 + (tx << 2);
        float4 ub = *(const float4*)&P.upd_b2[n];
        float4 h0 = *(const float4*)&P.h0g[b * HID + n];
        float v[4] = {acc[i][0] + ub.x + h0.x, acc[i][1] + ub.y + h0.y,
                      acc[i][2] + ub.z + h0.z, acc[i][3] + ub.w + h0.w};
        float4 o = {v[0], v[1], v[2], v[3]};
        *(float4*)&P.hu0[(size_t)m * HID + n] = o;
        stats_acc(s0, q0, m, v);
    }
}

// ---------------------------------------------------------------------------
// Triple GEMM with LN-on-load A: C{0,1,2} = LN(A) @ B{0,1,2} (+bias)
// grid 192: z = blk>>6, tile = blk&63
// ---------------------------------------------------------------------------
__global__ __launch_bounds__(256) void gemm3_kernel(
    const float* __restrict__ A, const float* __restrict__ ssum, const float* __restrict__ ssq,
    const float* __restrict__ lng, const float* __restrict__ lnb,
    const float* __restrict__ B0, const float* __restrict__ B1, const float* __restrict__ B2,
    const float* __restrict__ bias0, const float* __restrict__ bias1, const float* __restrict__ bias2,
    float* __restrict__ C0, float* __restrict__ C1, float* __restrict__ C2)
{
    __shared__ float As[16][68];
    __shared__ float Bs[16][64];
    int blk = blockIdx.x;
    int z = blk >> 6, tile = blk & 63;
    const float* B    = (z == 0) ? B0 : (z == 1) ? B1 : B2;
    const float* bias = (z == 0) ? bias0 : (z == 1) ? bias1 : bias2;
    float* C          = (z == 0) ? C0 : (z == 1) ? C1 : C2;
    int m0 = (tile >> 2) * 64, n0 = (tile & 3) * 64;
    float acc[4][4] = {};
    gemm_core(As, Bs, m0, n0, A, ssum, ssq, lng, lnb, B,
              nullptr, nullptr, nullptr, nullptr, acc);
    int t = threadIdx.x, ty = t >> 4, tx = t & 15;
#pragma unroll
    for (int i = 0; i < 4; ++i) {
        int m = m0 + (ty << 2) + i, n = n0 + (tx << 2);
        float4 o = {acc[i][0], acc[i][1], acc[i][2], acc[i][3]};
        if (bias) {
            float4 bb = *(const float4*)&bias[n];
            o.x += bb.x; o.y += bb.y; o.z += bb.z; o.w += bb.w;
        }
        *(float4*)&C[(size_t)m * HID + n] = o;
    }
}

// ---------------------------------------------------------------------------
// Fused aggregate + u1-GEMV:
//   aggpre[i0..i0+3][:] = sum_j Aw[i,j]*relu(a_i + bb_j + mb1)   (full rows)
//   u1[i][n] = relu(aggpre_i @ W2u[:,n] + P1[i,n] + rsum[i]*mb2u[n] + ub1[n])
// grid 256: b = blk>>5, i0 = (blk&31)*4
// ---------------------------------------------------------------------------
__global__ __launch_bounds__(256) void agg_u1_kernel(
    const float* __restrict__ a, const float* __restrict__ bbv,
    const float* __restrict__ mb1, const float* __restrict__ Aw,
    const float* __restrict__ P1, const float* __restrict__ W2u,
    const float* __restrict__ mb2u, const float* __restrict__ rsum,
    const float* __restrict__ ub1, float* __restrict__ u1)
{
    __shared__ float ap[4][256];
    int blk = blockIdx.x;
    int b  = blk >> 5;
    int i0 = (blk & 31) * 4;
    int h  = threadIdx.x;

    float bias = mb1[h];
    float ai[4], acc[4] = {0.f, 0.f, 0.f, 0.f};
#pragma unroll
    for (int ii = 0; ii < 4; ++ii)
        ai[ii] = a[((size_t)b * NR + i0 + ii) * HID + h] + bias;
    const float* bbb = &bbv[(size_t)b * NR * HID + h];
#pragma unroll 2
    for (int j = 0; j < NR; ++j) {
        float bj = bbb[(size_t)j * HID];
#pragma unroll
        for (int ii = 0; ii < 4; ++ii) {
            float pre = fmaxf(ai[ii] + bj, 0.0f);
            acc[ii] += Aw[(i0 + ii) * NR + j] * pre;
        }
    }
#pragma unroll
    for (int ii = 0; ii < 4; ++ii) ap[ii][h] = acc[ii];
    __syncthreads();

    // u1 part: thread h = output column n
    int n = h;
    float acc2[4] = {0.f, 0.f, 0.f, 0.f};
    for (int k0 = 0; k0 < HID; k0 += 4) {
        float w0 = W2u[(size_t)(k0 + 0) * HID + n];
        float w1 = W2u[(size_t)(k0 + 1) * HID + n];
        float w2 = W2u[(size_t)(k0 + 2) * HID + n];
        float w3 = W2u[(size_t)(k0 + 3) * HID + n];
#pragma unroll
        for (int ii = 0; ii < 4; ++ii) {
            float4 av = *(const float4*)&ap[ii][k0];
            acc2[ii] += av.x * w0 + av.y * w1 + av.z * w2 + av.w * w3;
        }
    }
    float mbv = mb2u[n], ubv = ub1[n];
#pragma unroll
    for (int ii = 0; ii < 4; ++ii) {
        size_t m = (size_t)b * NR + i0 + ii;
        float v = acc2[ii] + P1[m * HID + n] + rsum[i0 + ii] * mbv + ubv;
        u1[m * HID + n] = fmaxf(v, 0.0f);
    }
}

// ---------------------------------------------------------------------------
// Residual GEMM: hu_new = LN_prev(hu_prev) + (u1 @ uW2 + ub2); stats_new.
// ---------------------------------------------------------------------------
__global__ __launch_bounds__(256) void resid_gemm_kernel(
    const float* __restrict__ u1, const float* __restrict__ uW2,
    const float* __restrict__ ub2,
    const float* __restrict__ huprev, const float* __restrict__ sP,
    const float* __restrict__ qP, const float* __restrict__ lngp,
    const float* __restrict__ lnbp,
    float* __restrict__ hunew, float* __restrict__ sN, float* __restrict__ qN)
{
    __shared__ float As[16][68];
    __shared__ float Bs[16][64];
    int blk = blockIdx.x;
    int m0 = (blk >> 2) * 64, n0 = (blk & 3) * 64;
    float acc[4][4] = {};
    gemm_core(As, Bs, m0, n0, u1, nullptr, nullptr, nullptr, nullptr, uW2,
              nullptr, nullptr, nullptr, nullptr, acc);
    int t = threadIdx.x, ty = t >> 4, tx = t & 15;
    int n = n0 + (tx << 2);
    float4 ub = *(const float4*)&ub2[n];
    float4 g  = *(const float4*)&lngp[n];
    float4 bt = *(const float4*)&lnbp[n];
#pragma unroll
    for (int i = 0; i < 4; ++i) {
        int m = m0 + (ty << 2) + i;
        float sp = sP[m], qp = qP[m];
        float mup = sp * (1.0f / HID);
        float invp = rsqrtf(qp * (1.0f / HID) - mup * mup + 1e-5f);
        float4 hp = *(const float4*)&huprev[(size_t)m * HID + n];
        float v[4];
        v[0] = acc[i][0] + ub.x + (hp.x - mup) * invp * g.x + bt.x;
        v[1] = acc[i][1] + ub.y + (hp.y - mup) * invp * g.y + bt.y;
        v[2] = acc[i][2] + ub.z + (hp.z - mup) * invp * g.z + bt.z;
        v[3] = acc[i][3] + ub.w + (hp.w - mup) * invp * g.w + bt.w;
        float4 o = {v[0], v[1], v[2], v[3]};
        *(float4*)&hunew[(size_t)m * HID + n] = o;
        stats_acc(sN, qN, m, v);
    }
}

// ---------------------------------------------------------------------------
// Fused attention: blk = bh*8 + ig; 16 q-rows per block, one (b,head).
// ---------------------------------------------------------------------------
__global__ __launch_bounds__(256) void attention_kernel(
    const float* __restrict__ q, const float* __restrict__ k,
    const float* __restrict__ v, float* __restrict__ pooled)
{
    __shared__ struct { float KhT[64][128]; float S[16][128]; float qs[16][64]; } L;
    int blk = blockIdx.x;
    int bh = blk >> 3, ig = blk & 7;
    int b = bh >> 2, hd = bh & 3;
    int i0 = ig * 16;
    int t = threadIdx.x;
    const float* qg = q + ((size_t)b * NR) * HID + hd * DHD;
    const float* kg = k + ((size_t)b * NR) * HID + hd * DHD;
    const float* vg = v + ((size_t)b * NR) * HID + hd * DHD;

    {   // stage K^T
        int j = t >> 1, half = t & 1;
        const float* krow = kg + (size_t)j * HID + half * 32;
#pragma unroll
        for (int c = 0; c < 32; c += 4) {
            float4 kv = *(const float4*)(krow + c);
            L.KhT[half * 32 + c + 0][j] = kv.x;
            L.KhT[half * 32 + c + 1][j] = kv.y;
            L.KhT[half * 32 + c + 2][j] = kv.z;
            L.KhT[half * 32 + c + 3][j] = kv.w;
        }
    }
    {   // stage q rows
        int ii = t >> 4, d0 = (t & 15) * 4;
        *(float4*)&L.qs[ii][d0] = *(const float4*)(qg + (size_t)(i0 + ii) * HID + d0);
    }
    __syncthreads();
    {   // scores
        int j = t & 127, ii2 = t >> 7;
        float acc[8] = {0.f,0.f,0.f,0.f,0.f,0.f,0.f,0.f};
#pragma unroll 4
        for (int d = 0; d < 64; ++d) {
            float kv = L.KhT[d][j];
#pragma unroll
            for (int ii = 0; ii < 8; ++ii) acc[ii] += L.qs[ii2 * 8 + ii][d] * kv;
        }
#pragma unroll
        for (int ii = 0; ii < 8; ++ii) L.S[ii2 * 8 + ii][j] = acc[ii] * 0.125f;
    }
    __syncthreads();
    {   // softmax per row
        int w = t >> 6, l = t & 63;
#pragma unroll
        for (int r = w * 4; r < w * 4 + 4; ++r) {
            float e0 = L.S[r][l], e1 = L.S[r][l + 64];
            float mx = fmaxf(e0, e1);
#pragma unroll
            for (int off = 32; off; off >>= 1) mx = fmaxf(mx, __shfl_xor(mx, off));
            e0 = expf(e0 - mx); e1 = expf(e1 - mx);
            float sm = e0 + e1;
#pragma unroll
            for (int off = 32; off; off >>= 1) sm += __shfl_xor(sm, off);
            float inv = 1.0f / sm;
            L.S[r][l] = e0 * inv; L.S[r][l + 64] = e1 * inv;
        }
    }
    __syncthreads();
    {   // PV
        int d = t & 63, ir = t >> 6;
        float accv[4] = {0.f, 0.f, 0.f, 0.f};
        const float* vp = vg + d;
#pragma unroll 8
        for (int j = 0; j < NR; ++j) {
            float vv = vp[(size_t)j * HID];
#pragma unroll
            for (int p = 0; p < 4; ++p) accv[p] += L.S[p * 4 + ir][j] * vv;
        }
#pragma unroll
        for (int p = 0; p < 4; ++p)
            pooled[((size_t)(b * NR + i0 + p * 4 + ir)) * HID + hd * DHD + d] = accv[p];
    }
}

// ---------------------------------------------------------------------------
// Tail: g = mean_i pooled; @Wo+bo; relu(@roW1+rob1); @roW2+rob2; softmax.
// ---------------------------------------------------------------------------
__global__ __launch_bounds__(256) void tail_kernel(KP P) {
    __shared__ HdLds L;
    int b = blockIdx.x;
    int t = threadIdx.x;
    int w = t >> 6, l = t & 63;
    float* red = L.red;
    {   // mean over 128 rows
        float4 acc = {0.f, 0.f, 0.f, 0.f};
        const float* pb = &P.bufP1[((size_t)b * NR + w * 32) * HID + l * 4];
#pragma unroll 8
        for (int ii = 0; ii < 32; ++ii) {
            float4 pv = *(const float4*)(pb + (size_t)ii * HID);
            acc.x += pv.x; acc.y += pv.y; acc.z += pv.z; acc.w += pv.w;
        }
        *(float4*)&red[w * 256 + l * 4] = acc;
        __syncthreads();
        L.v0[t] = (red[t] + red[256 + t] + red[512 + t] + red[768 + t]) * (1.0f / NR);
        __syncthreads();
    }
    gemv256(L.v0, P.Wo, HID, P.bo, 0, L.v1, red);
    gemv256(L.v1, P.ro_W1, HID, P.ro_b1, 1, L.v2, red);
    {   // logits
        float2 acc = {0.f, 0.f};
        const float* Wp = P.ro_W2 + (size_t)(w * 64) * NR + l * 2;
        const float* xp = L.v2 + w * 64;
#pragma unroll 8
        for (int kk = 0; kk < 64; ++kk) {
            float xv = xp[kk];
            float2 wv = *(const float2*)(Wp + (size_t)kk * NR);
            acc.x += xv * wv.x; acc.y += xv * wv.y;
        }
        *(float2*)&red[w * 128 + l * 2] = acc;
        __syncthreads();
    }
    float logit = -1e30f;
    if (t < NR) logit = red[t] + red[128 + t] + red[256 + t] + red[384 + t] + P.ro_b2[t];
    __syncthreads();
    float m = logit;
#pragma unroll
    for (int off = 32; off; off >>= 1) m = fmaxf(m, __shfl_xor(m, off));
    if (l == 0) red[w] = m;
    __syncthreads();
    m = fmaxf(red[0], red[1]);
    float e = (t < NR) ? expf(logit - m) : 0.0f;
    float ssum = e;
#pragma unroll
    for (int off = 32; off; off >>= 1) ssum += __shfl_xor(ssum, off);
    if (l == 0) red[4 + w] = ssum;
    __syncthreads();
    float tot = red[4] + red[5];
    if (t < NR) P.out[b * NR + t] = e / tot;
}

// ---------------------------------------------------------------------------
extern "C" void kernel_launch(void* const* d_in, const int* in_sizes, int n_in,
                              void* d_out, int out_size, void* d_ws, size_t ws_size,
                              hipStream_t stream)
{
    KP P;
    P.x        = (const float*)d_in[0];
    P.We       = (const float*)d_in[1];
    P.be       = (const float*)d_in[2];
    P.msg_W1   = (const float*)d_in[3];
    P.msg_b1   = (const float*)d_in[4];
    P.msg_W2   = (const float*)d_in[5];
    P.msg_b2   = (const float*)d_in[6];
    P.upd_W1   = (const float*)d_in[7];
    P.upd_b1   = (const float*)d_in[8];
    P.upd_W2   = (const float*)d_in[9];
    P.upd_b2   = (const float*)d_in[10];
    P.ln_g     = (const float*)d_in[11];
    P.ln_b     = (const float*)d_in[12];
    P.rule_adj = (const float*)d_in[13];
    P.Wq       = (const float*)d_in[14];
    P.bq       = (const float*)d_in[15];
    P.Wk       = (const float*)d_in[16];
    P.bk       = (const float*)d_in[17];
    P.Wv       = (const float*)d_in[18];
    P.bv       = (const float*)d_in[19];
    P.Wo       = (const float*)d_in[20];
    P.bo       = (const float*)d_in[21];
    P.ro_W1    = (const float*)d_in[22];
    P.ro_b1    = (const float*)d_in[23];
    P.ro_W2    = (const float*)d_in[24];
    P.ro_b2    = (const float*)d_in[25];
    P.out      = (float*)d_out;

    float* b0 = (float*)d_ws;
    P.hu0    = b0;  b0 += SZ;
    P.hu1    = b0;  b0 += SZ;
    P.hu2    = b0;  b0 += SZ;
    P.bufA   = b0;  b0 += SZ;
    P.bufBB  = b0;  b0 += SZ;
    P.bufP1  = b0;  b0 += SZ;
    P.bufU1  = b0;  b0 += SZ;
    P.W2u    = b0;  b0 += 2 * HID * HID;
    P.mb2u   = b0;  b0 += 2 * HID;
    P.Aw     = b0;  b0 += NR * NR;
    P.rsum   = b0;  b0 += NR;
    P.h0g    = b0;  b0 += NB * HID;
    P.c0g    = b0;  b0 += NB * HID;
    P.c1g    = b0;  b0 += NB * HID;
    P.sts    = b0;  b0 += 3 * 2048;
    P.scratch= b0;  b0 += 256;

    const float* hu[3]  = {P.hu0, P.hu1, P.hu2};

    setup_kernel<<<dim3(256), 256, 0, stream>>>(P);
    layer0_kernel<<<dim3(64), 256, 0, stream>>>(P);

    for (int l = 1; l < 3; ++l) {
        const float* mW1 = P.msg_W1 + (size_t)l * 2 * HID * HID;
        const float* sP  = P.sts + (l - 1) * 2048;
        const float* qP  = sP + 1024;
        const float* lgp = P.ln_g + (size_t)(l - 1) * HID;
        const float* lbp = P.ln_b + (size_t)(l - 1) * HID;

        // a = N@mW1a ; bb = N@mW1b ; P1 = N@uW1a
        gemm3_kernel<<<dim3(192), 256, 0, stream>>>(
            hu[l - 1], sP, qP, lgp, lbp,
            mW1, mW1 + (size_t)HID * HID, P.upd_W1 + (size_t)l * 2 * HID * HID,
            nullptr, nullptr, nullptr,
            P.bufA, P.bufBB, P.bufP1);

        // aggregate + u1
        agg_u1_kernel<<<dim3(256), 256, 0, stream>>>(
            P.bufA, P.bufBB, P.msg_b1 + (size_t)l * HID, P.Aw,
            P.bufP1, P.W2u + (size_t)(l - 1) * HID * HID,
            P.mb2u + (l - 1) * HID, P.rsum, P.upd_b1 + (size_t)l * HID, P.bufU1);

        // hu_l = N_{l-1} + u1@uW2 + ub2 ; stats_l
        resid_gemm_kernel<<<dim3(64), 256, 0, stream>>>(
            P.bufU1, P.upd_W2 + (size_t)l * HID * HID, P.upd_b2 + (size_t)l * HID,
            hu[l - 1], sP, qP, lgp, lbp,
            (float*)hu[l], P.sts + l * 2048, P.sts + l * 2048 + 1024);
    }

    // qkv (LN-on-load with layer-2 stats)
    gemm3_kernel<<<dim3(192), 256, 0, stream>>>(
        hu[2], P.sts + 2 * 2048, P.sts + 2 * 2048 + 1024,
        P.ln_g + 2 * HID, P.ln_b + 2 * HID,
        P.Wq, P.Wk, P.Wv, P.bq, P.bk, P.bv,
        P.bufA, P.bufBB, P.bufU1);

    attention_kernel<<<dim3(256), 256, 0, stream>>>(P.bufA, P.bufBB, P.bufU1, P.bufP1);
    tail_kernel<<<dim3(8), 256, 0, stream>>>(P);
}

// Round 5
// 289.005 us; speedup vs baseline: 3.8312x; 1.0741x over previous
//
#include <hip/hip_runtime.h>
#include <math.h>

// Problem dims (fixed)
constexpr int NB  = 8;    // batch
constexpr int NR  = 128;  // rule nodes
constexpr int HID = 256;  // hidden
constexpr int NIN = 512;  // input dim
constexpr int DHD = 64;   // head dim
constexpr size_t SZ = (size_t)NB * NR * HID;  // 262144

struct KP {
    const float *x, *We, *be, *msg_W1, *msg_b1, *msg_W2, *msg_b2;
    const float *upd_W1, *upd_b1, *upd_W2, *upd_b2, *ln_g, *ln_b, *rule_adj;
    const float *Wq, *bq, *Wk, *bk, *Wv, *bv, *Wo, *bo, *ro_W1, *ro_b1, *ro_W2, *ro_b2;
    float* out;
    float *hu0, *hu1, *hu2;          // residual streams (pre-LN)
    float *bufA, *bufBB, *bufP1, *bufU1;
    float *W2u, *mb2u, *Aw, *rsum;
    float *h0g, *p0g, *m0g, *c0g, *c1g;
    float *gacc, *s1g, *s2g;         // tail vectors [8,256]
    float *sts;                      // [3][2][1024]: sum, sumsq per layer
    float *scratch;
};

// ---------------------------------------------------------------------------
// 64x64-tile fp32 GEMM core (K=256), register-double-buffered staging.
//  ssum != null: apply LN-on-load to A rows with stats + g/b.
// ---------------------------------------------------------------------------
__device__ __forceinline__ void gemm_core(
    float (&As)[16][68], float (&Bs)[16][64], int m0, int n0,
    const float* __restrict__ A,
    const float* __restrict__ ssum, const float* __restrict__ ssq,
    const float* __restrict__ lng, const float* __restrict__ lnb,
    const float* __restrict__ B,
    float (&acc)[4][4])
{
    int tid = threadIdx.x;
    int ty = tid >> 4, tx = tid & 15;
    int arow = tid >> 2, acol = (tid & 3) << 2;
    int brow = tid >> 4, bcol = (tid & 15) << 2;
    int m = m0 + arow;

    bool ln = (ssum != nullptr);
    float mu = 0.f, inv = 1.f;
    if (ln) {
        float s = ssum[m], q = ssq[m];
        mu = s * (1.0f / HID);
        inv = rsqrtf(q * (1.0f / HID) - mu * mu + 1e-5f);
    }

    auto loadA = [&](int k0) -> float4 {
        int kx = k0 + acol;
        float4 v = *(const float4*)&A[(size_t)m * HID + kx];
        if (ln) {
            float4 g = *(const float4*)(lng + kx);
            float4 b = *(const float4*)(lnb + kx);
            v.x = (v.x - mu) * inv * g.x + b.x;
            v.y = (v.y - mu) * inv * g.y + b.y;
            v.z = (v.z - mu) * inv * g.z + b.z;
            v.w = (v.w - mu) * inv * g.w + b.w;
        }
        return v;
    };

    float4 av = loadA(0);
    float4 bv = *(const float4*)&B[(size_t)brow * HID + n0 + bcol];

    for (int k0 = 0; k0 < HID; k0 += 16) {
        As[acol + 0][arow] = av.x;
        As[acol + 1][arow] = av.y;
        As[acol + 2][arow] = av.z;
        As[acol + 3][arow] = av.w;
        *(float4*)&Bs[brow][bcol] = bv;
        __syncthreads();
        float4 avn = av, bvn = bv;
        if (k0 + 16 < HID) {
            avn = loadA(k0 + 16);
            bvn = *(const float4*)&B[(size_t)(k0 + 16 + brow) * HID + n0 + bcol];
        }
#pragma unroll
        for (int kk = 0; kk < 16; ++kk) {
            float4 af = *(const float4*)&As[kk][ty << 2];
            float4 bf = *(const float4*)&Bs[kk][tx << 2];
            float a_[4] = {af.x, af.y, af.z, af.w};
            float b_[4] = {bf.x, bf.y, bf.z, bf.w};
#pragma unroll
            for (int i = 0; i < 4; ++i)
#pragma unroll
                for (int j = 0; j < 4; ++j) acc[i][j] += a_[i] * b_[j];
        }
        __syncthreads();
        av = avn; bv = bvn;
    }
}

// ---------------------------------------------------------------------------
// Setup: adjacency | W2u = mW2[l]@uW1b[l] | mb2u | headE (h0, distributed) |
// weight prefetch (poison evicts L3 every replay).
// ---------------------------------------------------------------------------
__global__ __launch_bounds__(256) void setup0_kernel(KP P) {
    __shared__ union {
        struct { float As[16][68]; float Bs[16][64]; } g;
        struct { float xs[NIN]; float part[8][32]; } e;
    } L;
    int blk = blockIdx.x;
    int t = threadIdx.x;

    if (blk < 32) {
        // adjacency: 4 rows per block
        int rr = blk * 4 + (t >> 6);
        int l = t & 63;
        float s_loc = 0.f;
#pragma unroll
        for (int rep = 0; rep < 2; ++rep) {
            int j = l + rep * 64;
            float xv = P.rule_adj[rr * NR + j];
            float sg = 1.0f / (1.0f + expf(-xv));
            if (j == rr) sg = 0.0f;
            P.Aw[rr * NR + j] = sg;
            s_loc += sg;
        }
#pragma unroll
        for (int off = 32; off; off >>= 1) s_loc += __shfl_xor(s_loc, off);
        if (l == 0) P.rsum[rr] = s_loc;
    } else if (blk < 64) {
        // W2u[l2] = msg_W2[1+l2] @ upd_W1b[1+l2]
        int idx = blk - 32, l2 = idx >> 4, t16 = idx & 15;
        int m0 = (t16 >> 2) * 64, n0 = (t16 & 3) * 64;
        float acc[4][4] = {};
        gemm_core(L.g.As, L.g.Bs, m0, n0,
                  P.msg_W2 + (size_t)(1 + l2) * HID * HID,
                  nullptr, nullptr, nullptr, nullptr,
                  P.upd_W1 + (size_t)(1 + l2) * 2 * HID * HID + (size_t)HID * HID,
                  acc);
        int ty = t >> 4, tx = t & 15;
        float* C = P.W2u + (size_t)l2 * HID * HID;
#pragma unroll
        for (int i = 0; i < 4; ++i) {
            int m = m0 + (ty << 2) + i, n = n0 + (tx << 2);
            float4 o = {acc[i][0], acc[i][1], acc[i][2], acc[i][3]};
            *(float4*)&C[(size_t)m * HID + n] = o;
        }
    } else if (blk < 66) {
        int l2 = blk - 64;
        const float* b2v = P.msg_b2 + (1 + l2) * HID;
        const float* Bm = P.upd_W1 + (size_t)(1 + l2) * 2 * HID * HID + (size_t)HID * HID;
        float acc = 0.f;
#pragma unroll 4
        for (int k = 0; k < HID; ++k) acc += b2v[k] * Bm[(size_t)k * HID + t];
        P.mb2u[l2 * HID + t] = acc;
    } else if (blk < 130) {
        // headE: h0[b] = x[b]@We + be, distributed (8 b x 8 col-slices)
        int idx = blk - 66;
        int b = idx >> 3, s = idx & 7;
        L.e.xs[t]       = P.x[b * NIN + t];
        L.e.xs[256 + t] = P.x[b * NIN + 256 + t];
        __syncthreads();
        int c = t & 31, seg = t >> 5;
        int col = s * 32 + c;
        const float* Wp = P.We + (size_t)(seg * 64) * HID + col;
        const float* xp = L.e.xs + seg * 64;
        float acc = 0.f;
#pragma unroll 16
        for (int k = 0; k < 64; ++k) acc += xp[k] * Wp[(size_t)k * HID];
        L.e.part[seg][c] = acc;
        __syncthreads();
        if (t < 32) {
            float v = 0.f;
#pragma unroll
            for (int sg = 0; sg < 8; ++sg) v += L.e.part[sg][t];
            int cc = s * 32 + t;
            P.h0g[b * HID + cc] = v + P.be[cc];
        }
    } else {
        // prefetch all weights -> warm L3
        int pfid = blk - 130, npf = 256 - 130;
        const float* arr[11] = {P.We, P.msg_W1, P.msg_W2, P.upd_W1, P.upd_W2,
                                P.Wq, P.Wk, P.Wv, P.Wo, P.ro_W1, P.ro_W2};
        const int n4[11] = {32768, 98304, 49152, 98304, 49152,
                            16384, 16384, 16384, 16384, 16384, 8192};
        float s = 0.f;
        for (int a = 0; a < 11; ++a) {
            const float4* p4 = (const float4*)arr[a];
            for (int i = pfid * 256 + t; i < n4[a]; i += npf * 256) {
                float4 v = p4[i];
                s += v.x + v.y + v.z + v.w;
            }
        }
        if (s == 1.0e37f) P.scratch[pfid] = s;  // keeps loads live
    }
}

// ---------------------------------------------------------------------------
// Distributed M=8 GEMV: out[b,col] = act((in[b,:]*scale) @ (W (+W2)) + bias)
// grid 64 (job A) or 128 (jobs A,B): z = blk>>6. block = (b, 32-col slice).
// K = 256 always (headA uses W2add to fold the duplicated-input K=512).
// ---------------------------------------------------------------------------
__global__ __launch_bounds__(256) void gemv8_kernel(
    const float* inA, const float* WA, const float* WA2, const float* biasA,
    float* outA, int reluA, float scaleA,
    const float* inB, const float* WB, const float* WB2, const float* biasB,
    float* outB, int reluB, float scaleB)
{
    __shared__ float xs[HID];
    __shared__ float part[8][32];
    int blk = blockIdx.x;
    int z = blk >> 6, bs = blk & 63;
    const float* in   = z ? inB : inA;
    const float* W    = z ? WB : WA;
    const float* W2   = z ? WB2 : WA2;
    const float* bias = z ? biasB : biasA;
    float* out        = z ? outB : outA;
    int relu    = z ? reluB : reluA;
    float scale = z ? scaleB : scaleA;

    int b = bs >> 3, s = bs & 7;
    int t = threadIdx.x;
    xs[t] = in[b * HID + t] * scale;
    __syncthreads();
    int c = t & 31, seg = t >> 5;
    int col = s * 32 + c;
    const float* Wp = W + (size_t)(seg * 32) * HID + col;
    const float* xp = xs + seg * 32;
    float acc = 0.f;
    if (W2) {
        const float* Wp2 = W2 + (size_t)(seg * 32) * HID + col;
#pragma unroll 8
        for (int k = 0; k < 32; ++k)
            acc += xp[k] * (Wp[(size_t)k * HID] + Wp2[(size_t)k * HID]);
    } else {
#pragma unroll 8
        for (int k = 0; k < 32; ++k)
            acc += xp[k] * Wp[(size_t)k * HID];
    }
    part[seg][c] = acc;
    __syncthreads();
    if (t < 32) {
        float v = 0.f;
#pragma unroll
        for (int sg = 0; sg < 8; ++sg) v += part[sg][t];
        int cc = s * 32 + t;
        if (bias) v += bias[cc];
        if (relu) v = fmaxf(v, 0.0f);
        out[b * HID + cc] = v;
    }
}

// ---------------------------------------------------------------------------
// rows4 @ W: out[ii] = rows[ii][:] dot W[:,n], n = threadIdx.x. W [256,256].
// rows in LDS (broadcast reads), W coalesced.
// ---------------------------------------------------------------------------
__device__ __forceinline__ void rows4_matmul(
    const float (&rows)[4][HID], const float* __restrict__ W, int n, float o[4])
{
    o[0] = o[1] = o[2] = o[3] = 0.f;
    for (int k0 = 0; k0 < HID; k0 += 4) {
        float w0 = W[(size_t)(k0 + 0) * HID + n];
        float w1 = W[(size_t)(k0 + 1) * HID + n];
        float w2 = W[(size_t)(k0 + 2) * HID + n];
        float w3 = W[(size_t)(k0 + 3) * HID + n];
#pragma unroll
        for (int ii = 0; ii < 4; ++ii) {
            float4 rv = *(const float4*)&rows[ii][k0];
            o[ii] += rv.x * w0 + rv.y * w1 + rv.z * w2 + rv.w * w3;
        }
    }
}

// Block-local row stats: thread holds v[ii] for rows m0+ii at its column.
__device__ __forceinline__ void row_stats4(
    float (&sred)[4][4][2], const float v[4], float* sts, float* stq, int m0)
{
    int w = threadIdx.x >> 6, l = threadIdx.x & 63;
    float s[4], q[4];
#pragma unroll
    for (int ii = 0; ii < 4; ++ii) { s[ii] = v[ii]; q[ii] = v[ii] * v[ii]; }
#pragma unroll
    for (int off = 32; off; off >>= 1) {
#pragma unroll
        for (int ii = 0; ii < 4; ++ii) {
            s[ii] += __shfl_xor(s[ii], off);
            q[ii] += __shfl_xor(q[ii], off);
        }
    }
    if (l == 0) {
#pragma unroll
        for (int ii = 0; ii < 4; ++ii) { sred[w][ii][0] = s[ii]; sred[w][ii][1] = q[ii]; }
    }
    __syncthreads();
    if (threadIdx.x < 8) {
        int row = threadIdx.x >> 1, isq = threadIdx.x & 1;
        float tot = sred[0][row][isq] + sred[1][row][isq] +
                    sred[2][row][isq] + sred[3][row][isq];
        (isq ? stq : sts)[m0 + row] = tot;
    }
}

// ---------------------------------------------------------------------------
// Layer 0 (collapsed): per block 4 rows.
//   u1[ii] = relu(c0[b] + rsum[i]*c1[b] + ub1)   (row in LDS)
//   hu0 = h0[b] + u1@uW2 + ub2 ; stats0 (block-local).
// ---------------------------------------------------------------------------
__global__ __launch_bounds__(256) void layer0r_kernel(KP P) {
    __shared__ float u1s[4][HID];
    __shared__ float sred[4][4][2];
    int blk = blockIdx.x;
    int m0 = blk * 4;
    int b = m0 >> 7, i0 = m0 & 127;
    int t = threadIdx.x;

    float c0v = P.c0g[b * HID + t];
    float c1v = P.c1g[b * HID + t];
    float ubv = P.upd_b1[t];
#pragma unroll
    for (int ii = 0; ii < 4; ++ii)
        u1s[ii][t] = fmaxf(c0v + P.rsum[i0 + ii] * c1v + ubv, 0.0f);
    __syncthreads();

    float u[4];
    rows4_matmul(u1s, P.upd_W2, t, u);

    float h0v = P.h0g[b * HID + t] + P.upd_b2[t];
    float v[4];
#pragma unroll
    for (int ii = 0; ii < 4; ++ii) {
        v[ii] = u[ii] + h0v;
        P.hu0[(size_t)(m0 + ii) * HID + t] = v[ii];
    }
    __syncthreads();
    row_stats4(sred, v, P.sts, P.sts + 1024, m0);
}

// ---------------------------------------------------------------------------
// Triple GEMM with LN-on-load A: C{0,1,2} = LN(A) @ B{0,1,2} (+bias). grid 192.
// ---------------------------------------------------------------------------
__global__ __launch_bounds__(256) void gemm3_kernel(
    const float* __restrict__ A, const float* __restrict__ ssum, const float* __restrict__ ssq,
    const float* __restrict__ lng, const float* __restrict__ lnb,
    const float* __restrict__ B0, const float* __restrict__ B1, const float* __restrict__ B2,
    const float* __restrict__ bias0, const float* __restrict__ bias1, const float* __restrict__ bias2,
    float* __restrict__ C0, float* __restrict__ C1, float* __restrict__ C2)
{
    __shared__ float As[16][68];
    __shared__ float Bs[16][64];
    int blk = blockIdx.x;
    int z = blk >> 6, tile = blk & 63;
    const float* B    = (z == 0) ? B0 : (z == 1) ? B1 : B2;
    const float* bias = (z == 0) ? bias0 : (z == 1) ? bias1 : bias2;
    float* C          = (z == 0) ? C0 : (z == 1) ? C1 : C2;
    int m0 = (tile >> 2) * 64, n0 = (tile & 3) * 64;
    float acc[4][4] = {};
    gemm_core(As, Bs, m0, n0, A, ssum, ssq, lng, lnb, B, acc);
    int t = threadIdx.x, ty = t >> 4, tx = t & 15;
#pragma unroll
    for (int i = 0; i < 4; ++i) {
        int m = m0 + (ty << 2) + i, n = n0 + (tx << 2);
        float4 o = {acc[i][0], acc[i][1], acc[i][2], acc[i][3]};
        if (bias) {
            float4 bb = *(const float4*)&bias[n];
            o.x += bb.x; o.y += bb.y; o.z += bb.z; o.w += bb.w;
        }
        *(float4*)&C[(size_t)m * HID + n] = o;
    }
}

// ---------------------------------------------------------------------------
// Fused aggregate + u1 + resid GEMM + LN stats. Per block: 4 complete rows.
//   aggpre = sum_j Aw[i,j]*relu(a_i + bb_j + mb1)
//   u1 = relu(aggpre@W2u + P1 + rsum*mb2u + ub1)
//   hu_new = LN_prev(hu_prev) + u1@uW2 + ub2 ; stats_new (block-local).
// ---------------------------------------------------------------------------
__global__ __launch_bounds__(256) void agg_u1r_kernel(
    const float* __restrict__ a, const float* __restrict__ bbv,
    const float* __restrict__ mb1, const float* __restrict__ Aw,
    const float* __restrict__ P1, const float* __restrict__ W2u,
    const float* __restrict__ mb2u, const float* __restrict__ rsum,
    const float* __restrict__ ub1,
    const float* __restrict__ uW2, const float* __restrict__ ub2,
    const float* __restrict__ huprev, const float* __restrict__ sP, const float* __restrict__ qP,
    const float* __restrict__ lngp, const float* __restrict__ lnbp,
    float* __restrict__ hunew, float* __restrict__ sN, float* __restrict__ qN,
    float* __restrict__ gzero)
{
    __shared__ float ap[4][HID];
    __shared__ float u1s[4][HID];
    __shared__ float sred[4][4][2];
    int blk = blockIdx.x;
    int b  = blk >> 5;
    int i0 = (blk & 31) * 4;
    int m0 = b * NR + i0;
    int t  = threadIdx.x;

    if (gzero && blk == 0) {
#pragma unroll
        for (int i = 0; i < 8; ++i) gzero[i * 256 + t] = 0.f;
    }

    // aggregate
    float bias = mb1[t];
    float ai[4], acc[4] = {0.f, 0.f, 0.f, 0.f};
#pragma unroll
    for (int ii = 0; ii < 4; ++ii)
        ai[ii] = a[(size_t)(m0 + ii) * HID + t] + bias;
    const float* bbb = &bbv[(size_t)b * NR * HID + t];
#pragma unroll 2
    for (int j = 0; j < NR; ++j) {
        float bj = bbb[(size_t)j * HID];
#pragma unroll
        for (int ii = 0; ii < 4; ++ii) {
            float pre = fmaxf(ai[ii] + bj, 0.0f);
            acc[ii] += Aw[(i0 + ii) * NR + j] * pre;
        }
    }
#pragma unroll
    for (int ii = 0; ii < 4; ++ii) ap[ii][t] = acc[ii];
    __syncthreads();

    // u1 = relu(aggpre@W2u + P1 + rsum*mb2u + ub1)
    float w2[4];
    rows4_matmul(ap, W2u, t, w2);
    float mbv = mb2u[t], ubv = ub1[t];
#pragma unroll
    for (int ii = 0; ii < 4; ++ii) {
        float vv = w2[ii] + P1[(size_t)(m0 + ii) * HID + t] + rsum[i0 + ii] * mbv + ubv;
        u1s[ii][t] = fmaxf(vv, 0.0f);
    }
    __syncthreads();

    // u = u1@uW2 ; hu_new = LN_prev(huprev) + u + ub2
    float u[4];
    rows4_matmul(u1s, uW2, t, u);

    float4 gb; // not vector path here; scalar per thread col
    (void)gb;
    float gv = lngp[t], btv = lnbp[t], ub2v = ub2[t];
    float v[4];
#pragma unroll
    for (int ii = 0; ii < 4; ++ii) {
        int m = m0 + ii;
        float sp = sP[m], qp = qP[m];
        float mup = sp * (1.0f / HID);
        float invp = rsqrtf(qp * (1.0f / HID) - mup * mup + 1e-5f);
        float hp = huprev[(size_t)m * HID + t];
        v[ii] = (hp - mup) * invp * gv + btv + u[ii] + ub2v;
        hunew[(size_t)m * HID + t] = v[ii];
    }
    __syncthreads();
    row_stats4(sred, v, sN, qN, m0);
}

// ---------------------------------------------------------------------------
// Fused attention + mean: blk = bh*8 + ig; 16 q-rows per block, one (b,head).
// Row-sums of attention output atomically accumulated into gacc[b,256].
// ---------------------------------------------------------------------------
__global__ __launch_bounds__(256) void attention_kernel(
    const float* __restrict__ q, const float* __restrict__ k,
    const float* __restrict__ v, float* __restrict__ gacc)
{
    __shared__ struct { float KhT[64][128]; float S[16][128]; float qs[16][64]; } L;
    int blk = blockIdx.x;
    int bh = blk >> 3, ig = blk & 7;
    int b = bh >> 2, hd = bh & 3;
    int i0 = ig * 16;
    int t = threadIdx.x;
    const float* qg = q + ((size_t)b * NR) * HID + hd * DHD;
    const float* kg = k + ((size_t)b * NR) * HID + hd * DHD;
    const float* vg = v + ((size_t)b * NR) * HID + hd * DHD;

    {   // stage K^T
        int j = t >> 1, half = t & 1;
        const float* krow = kg + (size_t)j * HID + half * 32;
#pragma unroll
        for (int c = 0; c < 32; c += 4) {
            float4 kv = *(const float4*)(krow + c);
            L.KhT[half * 32 + c + 0][j] = kv.x;
            L.KhT[half * 32 + c + 1][j] = kv.y;
            L.KhT[half * 32 + c + 2][j] = kv.z;
            L.KhT[half * 32 + c + 3][j] = kv.w;
        }
    }
    {   // stage q rows
        int ii = t >> 4, d0 = (t & 15) * 4;
        *(float4*)&L.qs[ii][d0] = *(const float4*)(qg + (size_t)(i0 + ii) * HID + d0);
    }
    __syncthreads();
    {   // scores
        int j = t & 127, ii2 = t >> 7;
        float acc[8] = {0.f,0.f,0.f,0.f,0.f,0.f,0.f,0.f};
#pragma unroll 4
        for (int d = 0; d < 64; ++d) {
            float kv = L.KhT[d][j];
#pragma unroll
            for (int ii = 0; ii < 8; ++ii) acc[ii] += L.qs[ii2 * 8 + ii][d] * kv;
        }
#pragma unroll
        for (int ii = 0; ii < 8; ++ii) L.S[ii2 * 8 + ii][j] = acc[ii] * 0.125f;
    }
    __syncthreads();
    {   // softmax per row
        int w = t >> 6, l = t & 63;
#pragma unroll
        for (int r = w * 4; r < w * 4 + 4; ++r) {
            float e0 = L.S[r][l], e1 = L.S[r][l + 64];
            float mx = fmaxf(e0, e1);
#pragma unroll
            for (int off = 32; off; off >>= 1) mx = fmaxf(mx, __shfl_xor(mx, off));
            e0 = expf(e0 - mx); e1 = expf(e1 - mx);
            float sm = e0 + e1;
#pragma unroll
            for (int off = 32; off; off >>= 1) sm += __shfl_xor(sm, off);
            float inv = 1.0f / sm;
            L.S[r][l] = e0 * inv; L.S[r][l + 64] = e1 * inv;
        }
    }
    __syncthreads();
    {   // PV + row-sum into gacc
        int d = t & 63, ir = t >> 6;
        float accv[4] = {0.f, 0.f, 0.f, 0.f};
        const float* vp = vg + d;
#pragma unroll 8
        for (int j = 0; j < NR; ++j) {
            float vv = vp[(size_t)j * HID];
#pragma unroll
            for (int p = 0; p < 4; ++p) accv[p] += L.S[p * 4 + ir][j] * vv;
        }
        float s = accv[0] + accv[1] + accv[2] + accv[3];
        atomicAdd(&gacc[b * HID + hd * DHD + d], s);
    }
}

// ---------------------------------------------------------------------------
// TailD: logits = s2@roW2 + rob2 (K=256, N=128); softmax -> out. 8 blocks.
// ---------------------------------------------------------------------------
__global__ __launch_bounds__(256) void taild_kernel(
    const float* __restrict__ s2g, const float* __restrict__ roW2,
    const float* __restrict__ rob2, float* __restrict__ out)
{
    __shared__ float xs[HID];
    __shared__ float red[256];
    __shared__ float sm[8];
    int b = blockIdx.x;
    int t = threadIdx.x;
    int w = t >> 6, l = t & 63;
    xs[t] = s2g[b * HID + t];
    __syncthreads();
    int n = t & 127, half = t >> 7;
    const float* Wp = roW2 + (size_t)(half * 128) * NR + n;
    const float* xp = xs + half * 128;
    float acc = 0.f;
#pragma unroll 8
    for (int k = 0; k < 128; ++k) acc += xp[k] * Wp[(size_t)k * NR];
    red[t] = acc;
    __syncthreads();
    float logit = -1e30f;
    if (t < NR) logit = red[t] + red[128 + t] + rob2[t];
    float mx = logit;
#pragma unroll
    for (int off = 32; off; off >>= 1) mx = fmaxf(mx, __shfl_xor(mx, off));
    if (l == 0) sm[w] = mx;
    __syncthreads();
    mx = fmaxf(sm[0], sm[1]);
    float e = (t < NR) ? expf(logit - mx) : 0.0f;
    float ss = e;
#pragma unroll
    for (int off = 32; off; off >>= 1) ss += __shfl_xor(ss, off);
    if (l == 0) sm[4 + w] = ss;
    __syncthreads();
    float tot = sm[4] + sm[5];
    if (t < NR) out[b * NR + t] = e / tot;
}

// ---------------------------------------------------------------------------
extern "C" void kernel_launch(void* const* d_in, const int* in_sizes, int n_in,
                              void* d_out, int out_size, void* d_ws, size_t ws_size,
                              hipStream_t stream)
{
    KP P;
    P.x        = (const float*)d_in[0];
    P.We       = (const float*)d_in[1];
    P.be       = (const float*)d_in[2];
    P.msg_W1   = (const float*)d_in[3];
    P.msg_b1   = (const float*)d_in[4];
    P.msg_W2   = (const float*)d_in[5];
    P.msg_b2   = (const float*)d_in[6];
    P.upd_W1   = (const float*)d_in[7];
    P.upd_b1   = (const float*)d_in[8];
    P.upd_W2   = (const float*)d_in[9];
    P.upd_b2   = (const float*)d_in[10];
    P.ln_g     = (const float*)d_in[11];
    P.ln_b     = (const float*)d_in[12];
    P.rule_adj = (const float*)d_in[13];
    P.Wq       = (const float*)d_in[14];
    P.bq       = (const float*)d_in[15];
    P.Wk       = (const float*)d_in[16];
    P.bk       = (const float*)d_in[17];
    P.Wv       = (const float*)d_in[18];
    P.bv       = (const float*)d_in[19];
    P.Wo       = (const float*)d_in[20];
    P.bo       = (const float*)d_in[21];
    P.ro_W1    = (const float*)d_in[22];
    P.ro_b1    = (const float*)d_in[23];
    P.ro_W2    = (const float*)d_in[24];
    P.ro_b2    = (const float*)d_in[25];
    P.out      = (float*)d_out;

    float* b0 = (float*)d_ws;
    P.hu0    = b0;  b0 += SZ;
    P.hu1    = b0;  b0 += SZ;
    P.hu2    = b0;  b0 += SZ;
    P.bufA   = b0;  b0 += SZ;
    P.bufBB  = b0;  b0 += SZ;
    P.bufP1  = b0;  b0 += SZ;
    P.bufU1  = b0;  b0 += SZ;
    P.W2u    = b0;  b0 += 2 * HID * HID;
    P.mb2u   = b0;  b0 += 2 * HID;
    P.Aw     = b0;  b0 += NR * NR;
    P.rsum   = b0;  b0 += NR;
    P.h0g    = b0;  b0 += NB * HID;
    P.p0g    = b0;  b0 += NB * HID;
    P.m0g    = b0;  b0 += NB * HID;
    P.c0g    = b0;  b0 += NB * HID;
    P.c1g    = b0;  b0 += NB * HID;
    P.gacc   = b0;  b0 += NB * HID;
    P.s1g    = b0;  b0 += NB * HID;
    P.s2g    = b0;  b0 += NB * HID;
    P.sts    = b0;  b0 += 3 * 2048;
    P.scratch= b0;  b0 += 256;

    const float* hu[3] = {P.hu0, P.hu1, P.hu2};

    // setup: adj | W2u | mb2u | h0 | prefetch
    setup0_kernel<<<dim3(256), 256, 0, stream>>>(P);

    // head stages (distributed M=8 GEMVs)
    gemv8_kernel<<<dim3(64), 256, 0, stream>>>(          // p0 = relu(h0@(W1a+W1b)+mb1)
        P.h0g, P.msg_W1, P.msg_W1 + (size_t)HID * HID, P.msg_b1, P.p0g, 1, 1.0f,
        nullptr, nullptr, nullptr, nullptr, nullptr, 0, 1.0f);
    gemv8_kernel<<<dim3(64), 256, 0, stream>>>(          // m0 = p0@mW2+mb2
        P.p0g, P.msg_W2, nullptr, P.msg_b2, P.m0g, 0, 1.0f,
        nullptr, nullptr, nullptr, nullptr, nullptr, 0, 1.0f);
    gemv8_kernel<<<dim3(128), 256, 0, stream>>>(         // c0 = h0@uW1a ; c1 = m0@uW1b
        P.h0g, P.upd_W1, nullptr, nullptr, P.c0g, 0, 1.0f,
        P.m0g, P.upd_W1 + (size_t)HID * HID, nullptr, nullptr, P.c1g, 0, 1.0f);

    // layer 0 (collapsed) -> hu0, sts0
    layer0r_kernel<<<dim3(256), 256, 0, stream>>>(P);

    // layers 1..2
    for (int l = 1; l < 3; ++l) {
        const float* mW1 = P.msg_W1 + (size_t)l * 2 * HID * HID;
        const float* sP  = P.sts + (l - 1) * 2048;
        const float* qP  = sP + 1024;
        const float* lgp = P.ln_g + (size_t)(l - 1) * HID;
        const float* lbp = P.ln_b + (size_t)(l - 1) * HID;

        gemm3_kernel<<<dim3(192), 256, 0, stream>>>(
            hu[l - 1], sP, qP, lgp, lbp,
            mW1, mW1 + (size_t)HID * HID, P.upd_W1 + (size_t)l * 2 * HID * HID,
            nullptr, nullptr, nullptr,
            P.bufA, P.bufBB, P.bufP1);

        agg_u1r_kernel<<<dim3(256), 256, 0, stream>>>(
            P.bufA, P.bufBB, P.msg_b1 + (size_t)l * HID, P.Aw,
            P.bufP1, P.W2u + (size_t)(l - 1) * HID * HID,
            P.mb2u + (l - 1) * HID, P.rsum, P.upd_b1 + (size_t)l * HID,
            P.upd_W2 + (size_t)l * HID * HID, P.upd_b2 + (size_t)l * HID,
            hu[l - 1], sP, qP, lgp, lbp,
            (float*)hu[l], P.sts + l * 2048, P.sts + l * 2048 + 1024,
            (l == 2) ? P.gacc : nullptr);
    }

    // qkv (LN-on-load with layer-2 stats)
    gemm3_kernel<<<dim3(192), 256, 0, stream>>>(
        hu[2], P.sts + 2 * 2048, P.sts + 2 * 2048 + 1024,
        P.ln_g + 2 * HID, P.ln_b + 2 * HID,
        P.Wq, P.Wk, P.Wv, P.bq, P.bk, P.bv,
        P.bufA, P.bufBB, P.bufU1);

    // attention + mean (atomic into gacc)
    attention_kernel<<<dim3(256), 256, 0, stream>>>(P.bufA, P.bufBB, P.bufU1, P.gacc);

    // tail: s1 = (g/128)@Wo+bo ; s2 = relu(s1@roW1+rob1) ; logits+softmax
    gemv8_kernel<<<dim3(64), 256, 0, stream>>>(
        P.gacc, P.Wo, nullptr, P.bo, P.s1g, 0, 1.0f / NR,
        nullptr, nullptr, nullptr, nullptr, nullptr, 0, 1.0f);
    gemv8_kernel<<<dim3(64), 256, 0, stream>>>(
        P.s1g, P.ro_W1, nullptr, P.ro_b1, P.s2g, 1, 1.0f,
        nullptr, nullptr, nullptr, nullptr, nullptr, 0, 1.0f);
    taild_kernel<<<dim3(8), 256, 0, stream>>>(P.s2g, P.ro_W2, P.ro_b2, P.out);
}

// Round 6
// 286.165 us; speedup vs baseline: 3.8692x; 1.0099x over previous
//
#include <hip/hip_runtime.h>
#include <math.h>

// Problem dims (fixed)
constexpr int NB  = 8;    // batch
constexpr int NR  = 128;  // rule nodes
constexpr int HID = 256;  // hidden
constexpr int NIN = 512;  // input dim
constexpr int DHD = 64;   // head dim
constexpr size_t SZ = (size_t)NB * NR * HID;  // 262144

struct KP {
    const float *x, *We, *be, *msg_W1, *msg_b1, *msg_W2, *msg_b2;
    const float *upd_W1, *upd_b1, *upd_W2, *upd_b2, *ln_g, *ln_b, *rule_adj;
    const float *Wq, *bq, *Wk, *bk, *Wv, *bv, *Wo, *bo, *ro_W1, *ro_b1, *ro_W2, *ro_b2;
    float* out;
    float *hu0, *hu1, *hu2;          // residual streams (pre-LN)
    float *bufA, *bufBB, *bufP1, *bufU1;
    float *W2u, *mb2u, *Aw, *rsum;   // W2u[l] = msg_W2[l]@upd_W1b[l], 3 mats
    float *h0g, *p0g, *c0g, *c1g;
    float *gacc, *s1g, *s2g;         // tail vectors [8,256]
    float *sts;                      // [3][2][1024]: sum, sumsq per layer
    float *scratch;
};

// ---------------------------------------------------------------------------
// 64x64-tile fp32 GEMM core (K=256), register-double-buffered staging.
//  ssum != null: apply LN-on-load to A rows with stats + g/b.
// ---------------------------------------------------------------------------
__device__ __forceinline__ void gemm_core(
    float (&As)[16][68], float (&Bs)[16][64], int m0, int n0,
    const float* __restrict__ A,
    const float* __restrict__ ssum, const float* __restrict__ ssq,
    const float* __restrict__ lng, const float* __restrict__ lnb,
    const float* __restrict__ B,
    float (&acc)[4][4])
{
    int tid = threadIdx.x;
    int ty = tid >> 4, tx = tid & 15;
    int arow = tid >> 2, acol = (tid & 3) << 2;
    int brow = tid >> 4, bcol = (tid & 15) << 2;
    int m = m0 + arow;

    bool ln = (ssum != nullptr);
    float mu = 0.f, inv = 1.f;
    if (ln) {
        float s = ssum[m], q = ssq[m];
        mu = s * (1.0f / HID);
        inv = rsqrtf(q * (1.0f / HID) - mu * mu + 1e-5f);
    }

    auto loadA = [&](int k0) -> float4 {
        int kx = k0 + acol;
        float4 v = *(const float4*)&A[(size_t)m * HID + kx];
        if (ln) {
            float4 g = *(const float4*)(lng + kx);
            float4 b = *(const float4*)(lnb + kx);
            v.x = (v.x - mu) * inv * g.x + b.x;
            v.y = (v.y - mu) * inv * g.y + b.y;
            v.z = (v.z - mu) * inv * g.z + b.z;
            v.w = (v.w - mu) * inv * g.w + b.w;
        }
        return v;
    };

    float4 av = loadA(0);
    float4 bv = *(const float4*)&B[(size_t)brow * HID + n0 + bcol];

    for (int k0 = 0; k0 < HID; k0 += 16) {
        As[acol + 0][arow] = av.x;
        As[acol + 1][arow] = av.y;
        As[acol + 2][arow] = av.z;
        As[acol + 3][arow] = av.w;
        *(float4*)&Bs[brow][bcol] = bv;
        __syncthreads();
        float4 avn = av, bvn = bv;
        if (k0 + 16 < HID) {
            avn = loadA(k0 + 16);
            bvn = *(const float4*)&B[(size_t)(k0 + 16 + brow) * HID + n0 + bcol];
        }
#pragma unroll
        for (int kk = 0; kk < 16; ++kk) {
            float4 af = *(const float4*)&As[kk][ty << 2];
            float4 bf = *(const float4*)&Bs[kk][tx << 2];
            float a_[4] = {af.x, af.y, af.z, af.w};
            float b_[4] = {bf.x, bf.y, bf.z, bf.w};
#pragma unroll
            for (int i = 0; i < 4; ++i)
#pragma unroll
                for (int j = 0; j < 4; ++j) acc[i][j] += a_[i] * b_[j];
        }
        __syncthreads();
        av = avn; bv = bvn;
    }
}

// ---------------------------------------------------------------------------
// Wave-split GEMV (tail): y[0..255] = act(xs @ W + bias). W row-major [256,256].
// Wave w owns K/4 rows; lane l covers outputs 4l..4l+3.
// ---------------------------------------------------------------------------
__device__ __forceinline__ void gemv256w(
    const float* xs, const float* __restrict__ W,
    const float* __restrict__ bias, int relu, float* ys, float* red)
{
    int tid = threadIdx.x;
    int w = tid >> 6, l = tid & 63;
    float4 acc = {0.f, 0.f, 0.f, 0.f};
    const float* Wp = W + (size_t)(w * 64) * HID + l * 4;
    const float* xp = xs + w * 64;
#pragma unroll 16
    for (int kk = 0; kk < 64; ++kk) {
        float xv = xp[kk];
        float4 wv = *(const float4*)(Wp + (size_t)kk * HID);
        acc.x += xv * wv.x; acc.y += xv * wv.y;
        acc.z += xv * wv.z; acc.w += xv * wv.w;
    }
    *(float4*)&red[w * 256 + l * 4] = acc;
    __syncthreads();
    float v = red[tid] + red[256 + tid] + red[512 + tid] + red[768 + tid];
    if (bias) v += bias[tid];
    if (relu) v = fmaxf(v, 0.0f);
    ys[tid] = v;
    __syncthreads();
}

// ---------------------------------------------------------------------------
// Setup: adjacency | W2u[l]=mW2[l]@uW1b[l] (l=0..2) | mb2u | headE (h0) |
// weight prefetch (poison evicts L3 every replay).
// ---------------------------------------------------------------------------
__global__ __launch_bounds__(256) void setup0_kernel(KP P) {
    __shared__ union {
        struct { float As[16][68]; float Bs[16][64]; } g;
        struct { float xs[NIN]; float part[8][32]; } e;
    } L;
    int blk = blockIdx.x;
    int t = threadIdx.x;

    if (blk < 32) {
        // adjacency: 4 rows per block
        int rr = blk * 4 + (t >> 6);
        int l = t & 63;
        float s_loc = 0.f;
#pragma unroll
        for (int rep = 0; rep < 2; ++rep) {
            int j = l + rep * 64;
            float xv = P.rule_adj[rr * NR + j];
            float sg = 1.0f / (1.0f + expf(-xv));
            if (j == rr) sg = 0.0f;
            P.Aw[rr * NR + j] = sg;
            s_loc += sg;
        }
#pragma unroll
        for (int off = 32; off; off >>= 1) s_loc += __shfl_xor(s_loc, off);
        if (l == 0) P.rsum[rr] = s_loc;
    } else if (blk < 80) {
        // W2u[l2] = msg_W2[l2] @ upd_W1b[l2], l2 = 0..2
        int idx = blk - 32, l2 = idx >> 4, t16 = idx & 15;
        int m0 = (t16 >> 2) * 64, n0 = (t16 & 3) * 64;
        float acc[4][4] = {};
        gemm_core(L.g.As, L.g.Bs, m0, n0,
                  P.msg_W2 + (size_t)l2 * HID * HID,
                  nullptr, nullptr, nullptr, nullptr,
                  P.upd_W1 + (size_t)l2 * 2 * HID * HID + (size_t)HID * HID,
                  acc);
        int ty = t >> 4, tx = t & 15;
        float* C = P.W2u + (size_t)l2 * HID * HID;
#pragma unroll
        for (int i = 0; i < 4; ++i) {
            int m = m0 + (ty << 2) + i, n = n0 + (tx << 2);
            float4 o = {acc[i][0], acc[i][1], acc[i][2], acc[i][3]};
            *(float4*)&C[(size_t)m * HID + n] = o;
        }
    } else if (blk < 83) {
        int l2 = blk - 80;
        const float* b2v = P.msg_b2 + l2 * HID;
        const float* Bm = P.upd_W1 + (size_t)l2 * 2 * HID * HID + (size_t)HID * HID;
        float acc = 0.f;
#pragma unroll 4
        for (int k = 0; k < HID; ++k) acc += b2v[k] * Bm[(size_t)k * HID + t];
        P.mb2u[l2 * HID + t] = acc;
    } else if (blk < 147) {
        // headE: h0[b] = x[b]@We + be, distributed (8 b x 8 col-slices)
        int idx = blk - 83;
        int b = idx >> 3, s = idx & 7;
        L.e.xs[t]       = P.x[b * NIN + t];
        L.e.xs[256 + t] = P.x[b * NIN + 256 + t];
        __syncthreads();
        int c = t & 31, seg = t >> 5;
        int col = s * 32 + c;
        const float* Wp = P.We + (size_t)(seg * 64) * HID + col;
        const float* xp = L.e.xs + seg * 64;
        float acc = 0.f;
#pragma unroll 16
        for (int k = 0; k < 64; ++k) acc += xp[k] * Wp[(size_t)k * HID];
        L.e.part[seg][c] = acc;
        __syncthreads();
        if (t < 32) {
            float v = 0.f;
#pragma unroll
            for (int sg = 0; sg < 8; ++sg) v += L.e.part[sg][t];
            int cc = s * 32 + t;
            P.h0g[b * HID + cc] = v + P.be[cc];
        }
    } else {
        // prefetch all weights -> warm L3
        int pfid = blk - 147, npf = 256 - 147;
        const float* arr[11] = {P.We, P.msg_W1, P.msg_W2, P.upd_W1, P.upd_W2,
                                P.Wq, P.Wk, P.Wv, P.Wo, P.ro_W1, P.ro_W2};
        const int n4[11] = {32768, 98304, 49152, 98304, 49152,
                            16384, 16384, 16384, 16384, 16384, 8192};
        float s = 0.f;
        for (int a = 0; a < 11; ++a) {
            const float4* p4 = (const float4*)arr[a];
            for (int i = pfid * 256 + t; i < n4[a]; i += npf * 256) {
                float4 v = p4[i];
                s += v.x + v.y + v.z + v.w;
            }
        }
        if (s == 1.0e37f) P.scratch[pfid] = s;  // keeps loads live
    }
}

// ---------------------------------------------------------------------------
// Distributed M=8 GEMV: out[b,col] = act((in[b,:]*scale) @ (W (+W2)) + bias)
// grid 64 (job A) or 128 (jobs A,B): z = blk>>6. block = (b, 32-col slice).
// ---------------------------------------------------------------------------
__global__ __launch_bounds__(256) void gemv8_kernel(
    const float* inA, const float* WA, const float* WA2, const float* biasA,
    float* outA, int reluA, float scaleA,
    const float* inB, const float* WB, const float* WB2, const float* biasB,
    float* outB, int reluB, float scaleB)
{
    __shared__ float xs[HID];
    __shared__ float part[8][32];
    int blk = blockIdx.x;
    int z = blk >> 6, bs = blk & 63;
    const float* in   = z ? inB : inA;
    const float* W    = z ? WB : WA;
    const float* W2   = z ? WB2 : WA2;
    const float* bias = z ? biasB : biasA;
    float* out        = z ? outB : outA;
    int relu    = z ? reluB : reluA;
    float scale = z ? scaleB : scaleA;

    int b = bs >> 3, s = bs & 7;
    int t = threadIdx.x;
    xs[t] = in[b * HID + t] * scale;
    __syncthreads();
    int c = t & 31, seg = t >> 5;
    int col = s * 32 + c;
    const float* Wp = W + (size_t)(seg * 32) * HID + col;
    const float* xp = xs + seg * 32;
    float acc = 0.f;
    if (W2) {
        const float* Wp2 = W2 + (size_t)(seg * 32) * HID + col;
#pragma unroll 8
        for (int k = 0; k < 32; ++k)
            acc += xp[k] * (Wp[(size_t)k * HID] + Wp2[(size_t)k * HID]);
    } else {
#pragma unroll 8
        for (int k = 0; k < 32; ++k)
            acc += xp[k] * Wp[(size_t)k * HID];
    }
    part[seg][c] = acc;
    __syncthreads();
    if (t < 32) {
        float v = 0.f;
#pragma unroll
        for (int sg = 0; sg < 8; ++sg) v += part[sg][t];
        int cc = s * 32 + t;
        if (bias) v += bias[cc];
        if (relu) v = fmaxf(v, 0.0f);
        out[b * HID + cc] = v;
    }
}

// ---------------------------------------------------------------------------
// rows4 @ W: out[ii] = rows[ii][:] dot W[:,n], n = threadIdx.x. W [256,256].
// ---------------------------------------------------------------------------
__device__ __forceinline__ void rows4_matmul(
    const float (&rows)[4][HID], const float* __restrict__ W, int n, float o[4])
{
    o[0] = o[1] = o[2] = o[3] = 0.f;
    for (int k0 = 0; k0 < HID; k0 += 4) {
        float w0 = W[(size_t)(k0 + 0) * HID + n];
        float w1 = W[(size_t)(k0 + 1) * HID + n];
        float w2 = W[(size_t)(k0 + 2) * HID + n];
        float w3 = W[(size_t)(k0 + 3) * HID + n];
#pragma unroll
        for (int ii = 0; ii < 4; ++ii) {
            float4 rv = *(const float4*)&rows[ii][k0];
            o[ii] += rv.x * w0 + rv.y * w1 + rv.z * w2 + rv.w * w3;
        }
    }
}

// Block-local row stats: thread holds v[ii] for rows m0+ii at its column.
__device__ __forceinline__ void row_stats4(
    float (&sred)[4][4][2], const float v[4], float* sts, float* stq, int m0)
{
    int w = threadIdx.x >> 6, l = threadIdx.x & 63;
    float s[4], q[4];
#pragma unroll
    for (int ii = 0; ii < 4; ++ii) { s[ii] = v[ii]; q[ii] = v[ii] * v[ii]; }
#pragma unroll
    for (int off = 32; off; off >>= 1) {
#pragma unroll
        for (int ii = 0; ii < 4; ++ii) {
            s[ii] += __shfl_xor(s[ii], off);
            q[ii] += __shfl_xor(q[ii], off);
        }
    }
    if (l == 0) {
#pragma unroll
        for (int ii = 0; ii < 4; ++ii) { sred[w][ii][0] = s[ii]; sred[w][ii][1] = q[ii]; }
    }
    __syncthreads();
    if (threadIdx.x < 8) {
        int row = threadIdx.x >> 1, isq = threadIdx.x & 1;
        float tot = sred[0][row][isq] + sred[1][row][isq] +
                    sred[2][row][isq] + sred[3][row][isq];
        (isq ? stq : sts)[m0 + row] = tot;
    }
}

// ---------------------------------------------------------------------------
// Layer 0 (collapsed): per block 4 rows.
//   u1[ii] = relu(c0[b] + rsum[i]*c1[b] + ub1)
//   hu0 = h0[b] + u1@uW2 + ub2 ; stats0 (block-local).
// ---------------------------------------------------------------------------
__global__ __launch_bounds__(256) void layer0r_kernel(KP P) {
    __shared__ float u1s[4][HID];
    __shared__ float sred[4][4][2];
    int blk = blockIdx.x;
    int m0 = blk * 4;
    int b = m0 >> 7, i0 = m0 & 127;
    int t = threadIdx.x;

    float c0v = P.c0g[b * HID + t];
    float c1v = P.c1g[b * HID + t];
    float ubv = P.upd_b1[t];
#pragma unroll
    for (int ii = 0; ii < 4; ++ii)
        u1s[ii][t] = fmaxf(c0v + P.rsum[i0 + ii] * c1v + ubv, 0.0f);
    __syncthreads();

    float u[4];
    rows4_matmul(u1s, P.upd_W2, t, u);

    float h0v = P.h0g[b * HID + t] + P.upd_b2[t];
    float v[4];
#pragma unroll
    for (int ii = 0; ii < 4; ++ii) {
        v[ii] = u[ii] + h0v;
        P.hu0[(size_t)(m0 + ii) * HID + t] = v[ii];
    }
    __syncthreads();
    row_stats4(sred, v, P.sts, P.sts + 1024, m0);
}

// ---------------------------------------------------------------------------
// Triple GEMM with LN-on-load A: C{0,1,2} = LN(A) @ B{0,1,2} (+bias). grid 192.
// ---------------------------------------------------------------------------
__global__ __launch_bounds__(256) void gemm3_kernel(
    const float* __restrict__ A, const float* __restrict__ ssum, const float* __restrict__ ssq,
    const float* __restrict__ lng, const float* __restrict__ lnb,
    const float* __restrict__ B0, const float* __restrict__ B1, const float* __restrict__ B2,
    const float* __restrict__ bias0, const float* __restrict__ bias1, const float* __restrict__ bias2,
    float* __restrict__ C0, float* __restrict__ C1, float* __restrict__ C2)
{
    __shared__ float As[16][68];
    __shared__ float Bs[16][64];
    int blk = blockIdx.x;
    int z = blk >> 6, tile = blk & 63;
    const float* B    = (z == 0) ? B0 : (z == 1) ? B1 : B2;
    const float* bias = (z == 0) ? bias0 : (z == 1) ? bias1 : bias2;
    float* C          = (z == 0) ? C0 : (z == 1) ? C1 : C2;
    int m0 = (tile >> 2) * 64, n0 = (tile & 3) * 64;
    float acc[4][4] = {};
    gemm_core(As, Bs, m0, n0, A, ssum, ssq, lng, lnb, B, acc);
    int t = threadIdx.x, ty = t >> 4, tx = t & 15;
#pragma unroll
    for (int i = 0; i < 4; ++i) {
        int m = m0 + (ty << 2) + i, n = n0 + (tx << 2);
        float4 o = {acc[i][0], acc[i][1], acc[i][2], acc[i][3]};
        if (bias) {
            float4 bb = *(const float4*)&bias[n];
            o.x += bb.x; o.y += bb.y; o.z += bb.z; o.w += bb.w;
        }
        *(float4*)&C[(size_t)m * HID + n] = o;
    }
}

// ---------------------------------------------------------------------------
// Fused aggregate + u1 + resid GEMM + LN stats. Per block: 4 complete rows.
// ---------------------------------------------------------------------------
__global__ __launch_bounds__(256) void agg_u1r_kernel(
    const float* __restrict__ a, const float* __restrict__ bbv,
    const float* __restrict__ mb1, const float* __restrict__ Aw,
    const float* __restrict__ P1, const float* __restrict__ W2u,
    const float* __restrict__ mb2u, const float* __restrict__ rsum,
    const float* __restrict__ ub1,
    const float* __restrict__ uW2, const float* __restrict__ ub2,
    const float* __restrict__ huprev, const float* __restrict__ sP, const float* __restrict__ qP,
    const float* __restrict__ lngp, const float* __restrict__ lnbp,
    float* __restrict__ hunew, float* __restrict__ sN, float* __restrict__ qN,
    float* __restrict__ gzero)
{
    __shared__ float ap[4][HID];
    __shared__ float u1s[4][HID];
    __shared__ float sred[4][4][2];
    int blk = blockIdx.x;
    int b  = blk >> 5;
    int i0 = (blk & 31) * 4;
    int m0 = b * NR + i0;
    int t  = threadIdx.x;

    if (gzero && blk == 0) {
#pragma unroll
        for (int i = 0; i < 8; ++i) gzero[i * 256 + t] = 0.f;
    }

    // aggregate
    float bias = mb1[t];
    float ai[4], acc[4] = {0.f, 0.f, 0.f, 0.f};
#pragma unroll
    for (int ii = 0; ii < 4; ++ii)
        ai[ii] = a[(size_t)(m0 + ii) * HID + t] + bias;
    const float* bbb = &bbv[(size_t)b * NR * HID + t];
#pragma unroll 2
    for (int j = 0; j < NR; ++j) {
        float bj = bbb[(size_t)j * HID];
#pragma unroll
        for (int ii = 0; ii < 4; ++ii) {
            float pre = fmaxf(ai[ii] + bj, 0.0f);
            acc[ii] += Aw[(i0 + ii) * NR + j] * pre;
        }
    }
#pragma unroll
    for (int ii = 0; ii < 4; ++ii) ap[ii][t] = acc[ii];
    __syncthreads();

    // u1 = relu(aggpre@W2u + P1 + rsum*mb2u + ub1)
    float w2[4];
    rows4_matmul(ap, W2u, t, w2);
    float mbv = mb2u[t], ubv = ub1[t];
#pragma unroll
    for (int ii = 0; ii < 4; ++ii) {
        float vv = w2[ii] + P1[(size_t)(m0 + ii) * HID + t] + rsum[i0 + ii] * mbv + ubv;
        u1s[ii][t] = fmaxf(vv, 0.0f);
    }
    __syncthreads();

    // u = u1@uW2 ; hu_new = LN_prev(huprev) + u + ub2
    float u[4];
    rows4_matmul(u1s, uW2, t, u);

    float gv = lngp[t], btv = lnbp[t], ub2v = ub2[t];
    float v[4];
#pragma unroll
    for (int ii = 0; ii < 4; ++ii) {
        int m = m0 + ii;
        float sp = sP[m], qp = qP[m];
        float mup = sp * (1.0f / HID);
        float invp = rsqrtf(qp * (1.0f / HID) - mup * mup + 1e-5f);
        float hp = huprev[(size_t)m * HID + t];
        v[ii] = (hp - mup) * invp * gv + btv + u[ii] + ub2v;
        hunew[(size_t)m * HID + t] = v[ii];
    }
    __syncthreads();
    row_stats4(sred, v, sN, qN, m0);
}

// ---------------------------------------------------------------------------
// Fused attention + mean: blk = bh*8 + ig; 16 q-rows per block, one (b,head).
// Row-sums of attention output atomically accumulated into gacc[b,256].
// ---------------------------------------------------------------------------
__global__ __launch_bounds__(256) void attention_kernel(
    const float* __restrict__ q, const float* __restrict__ k,
    const float* __restrict__ v, float* __restrict__ gacc)
{
    __shared__ struct { float KhT[64][128]; float S[16][128]; float qs[16][64]; } L;
    int blk = blockIdx.x;
    int bh = blk >> 3, ig = blk & 7;
    int b = bh >> 2, hd = bh & 3;
    int i0 = ig * 16;
    int t = threadIdx.x;
    const float* qg = q + ((size_t)b * NR) * HID + hd * DHD;
    const float* kg = k + ((size_t)b * NR) * HID + hd * DHD;
    const float* vg = v + ((size_t)b * NR) * HID + hd * DHD;

    {   // stage K^T
        int j = t >> 1, half = t & 1;
        const float* krow = kg + (size_t)j * HID + half * 32;
#pragma unroll
        for (int c = 0; c < 32; c += 4) {
            float4 kv = *(const float4*)(krow + c);
            L.KhT[half * 32 + c + 0][j] = kv.x;
            L.KhT[half * 32 + c + 1][j] = kv.y;
            L.KhT[half * 32 + c + 2][j] = kv.z;
            L.KhT[half * 32 + c + 3][j] = kv.w;
        }
    }
    {   // stage q rows
        int ii = t >> 4, d0 = (t & 15) * 4;
        *(float4*)&L.qs[ii][d0] = *(const float4*)(qg + (size_t)(i0 + ii) * HID + d0);
    }
    __syncthreads();
    {   // scores
        int j = t & 127, ii2 = t >> 7;
        float acc[8] = {0.f,0.f,0.f,0.f,0.f,0.f,0.f,0.f};
#pragma unroll 4
        for (int d = 0; d < 64; ++d) {
            float kv = L.KhT[d][j];
#pragma unroll
            for (int ii = 0; ii < 8; ++ii) acc[ii] += L.qs[ii2 * 8 + ii][d] * kv;
        }
#pragma unroll
        for (int ii = 0; ii < 8; ++ii) L.S[ii2 * 8 + ii][j] = acc[ii] * 0.125f;
    }
    __syncthreads();
    {   // softmax per row
        int w = t >> 6, l = t & 63;
#pragma unroll
        for (int r = w * 4; r < w * 4 + 4; ++r) {
            float e0 = L.S[r][l], e1 = L.S[r][l + 64];
            float mx = fmaxf(e0, e1);
#pragma unroll
            for (int off = 32; off; off >>= 1) mx = fmaxf(mx, __shfl_xor(mx, off));
            e0 = expf(e0 - mx); e1 = expf(e1 - mx);
            float sm = e0 + e1;
#pragma unroll
            for (int off = 32; off; off >>= 1) sm += __shfl_xor(sm, off);
            float inv = 1.0f / sm;
            L.S[r][l] = e0 * inv; L.S[r][l + 64] = e1 * inv;
        }
    }
    __syncthreads();
    {   // PV + row-sum into gacc
        int d = t & 63, ir = t >> 6;
        float accv[4] = {0.f, 0.f, 0.f, 0.f};
        const float* vp = vg + d;
#pragma unroll 8
        for (int j = 0; j < NR; ++j) {
            float vv = vp[(size_t)j * HID];
#pragma unroll
            for (int p = 0; p < 4; ++p) accv[p] += L.S[p * 4 + ir][j] * vv;
        }
        float s = accv[0] + accv[1] + accv[2] + accv[3];
        atomicAdd(&gacc[b * HID + hd * DHD + d], s);
    }
}

// ---------------------------------------------------------------------------
// Fused tail: per-batch chain s1 = (g/128)@Wo+bo; s2 = relu(s1@roW1+rob1);
// logits = s2@roW2+rob2; softmax -> out. 8 blocks.
// ---------------------------------------------------------------------------
__global__ __launch_bounds__(256) void tailf_kernel(KP P) {
    __shared__ float v0[HID], v1[HID], v2[HID];
    __shared__ float red[1024];
    int b = blockIdx.x;
    int t = threadIdx.x;
    int w = t >> 6, l = t & 63;

    v0[t] = P.gacc[b * HID + t] * (1.0f / NR);
    __syncthreads();
    gemv256w(v0, P.Wo, P.bo, 0, v1, red);
    gemv256w(v1, P.ro_W1, P.ro_b1, 1, v2, red);

    {   // logits: N=128; lane l -> outputs 2l,2l+1; wave w -> K quarter
        float2 acc = {0.f, 0.f};
        const float* Wp = P.ro_W2 + (size_t)(w * 64) * NR + l * 2;
        const float* xp = v2 + w * 64;
#pragma unroll 8
        for (int kk = 0; kk < 64; ++kk) {
            float xv = xp[kk];
            float2 wv = *(const float2*)(Wp + (size_t)kk * NR);
            acc.x += xv * wv.x; acc.y += xv * wv.y;
        }
        *(float2*)&red[w * 128 + l * 2] = acc;
        __syncthreads();
    }
    float logit = -1e30f;
    if (t < NR) logit = red[t] + red[128 + t] + red[256 + t] + red[384 + t] + P.ro_b2[t];
    __syncthreads();
    float m = logit;
#pragma unroll
    for (int off = 32; off; off >>= 1) m = fmaxf(m, __shfl_xor(m, off));
    if (l == 0) red[w] = m;
    __syncthreads();
    m = fmaxf(red[0], red[1]);
    float e = (t < NR) ? expf(logit - m) : 0.0f;
    float ssum = e;
#pragma unroll
    for (int off = 32; off; off >>= 1) ssum += __shfl_xor(ssum, off);
    if (l == 0) red[4 + w] = ssum;
    __syncthreads();
    float tot = red[4] + red[5];
    if (t < NR) P.out[b * NR + t] = e / tot;
}

// ---------------------------------------------------------------------------
extern "C" void kernel_launch(void* const* d_in, const int* in_sizes, int n_in,
                              void* d_out, int out_size, void* d_ws, size_t ws_size,
                              hipStream_t stream)
{
    KP P;
    P.x        = (const float*)d_in[0];
    P.We       = (const float*)d_in[1];
    P.be       = (const float*)d_in[2];
    P.msg_W1   = (const float*)d_in[3];
    P.msg_b1   = (const float*)d_in[4];
    P.msg_W2   = (const float*)d_in[5];
    P.msg_b2   = (const float*)d_in[6];
    P.upd_W1   = (const float*)d_in[7];
    P.upd_b1   = (const float*)d_in[8];
    P.upd_W2   = (const float*)d_in[9];
    P.upd_b2   = (const float*)d_in[10];
    P.ln_g     = (const float*)d_in[11];
    P.ln_b     = (const float*)d_in[12];
    P.rule_adj = (const float*)d_in[13];
    P.Wq       = (const float*)d_in[14];
    P.bq       = (const float*)d_in[15];
    P.Wk       = (const float*)d_in[16];
    P.bk       = (const float*)d_in[17];
    P.Wv       = (const float*)d_in[18];
    P.bv       = (const float*)d_in[19];
    P.Wo       = (const float*)d_in[20];
    P.bo       = (const float*)d_in[21];
    P.ro_W1    = (const float*)d_in[22];
    P.ro_b1    = (const float*)d_in[23];
    P.ro_W2    = (const float*)d_in[24];
    P.ro_b2    = (const float*)d_in[25];
    P.out      = (float*)d_out;

    float* b0 = (float*)d_ws;
    P.hu0    = b0;  b0 += SZ;
    P.hu1    = b0;  b0 += SZ;
    P.hu2    = b0;  b0 += SZ;
    P.bufA   = b0;  b0 += SZ;
    P.bufBB  = b0;  b0 += SZ;
    P.bufP1  = b0;  b0 += SZ;
    P.bufU1  = b0;  b0 += SZ;
    P.W2u    = b0;  b0 += 3 * HID * HID;
    P.mb2u   = b0;  b0 += 3 * HID;
    P.Aw     = b0;  b0 += NR * NR;
    P.rsum   = b0;  b0 += NR;
    P.h0g    = b0;  b0 += NB * HID;
    P.p0g    = b0;  b0 += NB * HID;
    P.c0g    = b0;  b0 += NB * HID;
    P.c1g    = b0;  b0 += NB * HID;
    P.gacc   = b0;  b0 += NB * HID;
    P.s1g    = b0;  b0 += NB * HID;
    P.s2g    = b0;  b0 += NB * HID;
    P.sts    = b0;  b0 += 3 * 2048;
    P.scratch= b0;  b0 += 256;

    const float* hu[3] = {P.hu0, P.hu1, P.hu2};

    // 1. setup: adj | W2u (3 layers) | mb2u | h0 | prefetch
    setup0_kernel<<<dim3(256), 256, 0, stream>>>(P);

    // 2. p0 = relu(h0@(W1a+W1b)+mb1)  ||  c0 = h0@uW1a
    gemv8_kernel<<<dim3(128), 256, 0, stream>>>(
        P.h0g, P.msg_W1, P.msg_W1 + (size_t)HID * HID, P.msg_b1, P.p0g, 1, 1.0f,
        P.h0g, P.upd_W1, nullptr, nullptr, P.c0g, 0, 1.0f);

    // 3. c1 = p0@W2u0 + mb2u0   (m0 stage folded away)
    gemv8_kernel<<<dim3(64), 256, 0, stream>>>(
        P.p0g, P.W2u, nullptr, P.mb2u, P.c1g, 0, 1.0f,
        nullptr, nullptr, nullptr, nullptr, nullptr, 0, 1.0f);

    // 4. layer 0 (collapsed) -> hu0, sts0
    layer0r_kernel<<<dim3(256), 256, 0, stream>>>(P);

    // 5-8. layers 1..2
    for (int l = 1; l < 3; ++l) {
        const float* mW1 = P.msg_W1 + (size_t)l * 2 * HID * HID;
        const float* sP  = P.sts + (l - 1) * 2048;
        const float* qP  = sP + 1024;
        const float* lgp = P.ln_g + (size_t)(l - 1) * HID;
        const float* lbp = P.ln_b + (size_t)(l - 1) * HID;

        gemm3_kernel<<<dim3(192), 256, 0, stream>>>(
            hu[l - 1], sP, qP, lgp, lbp,
            mW1, mW1 + (size_t)HID * HID, P.upd_W1 + (size_t)l * 2 * HID * HID,
            nullptr, nullptr, nullptr,
            P.bufA, P.bufBB, P.bufP1);

        agg_u1r_kernel<<<dim3(256), 256, 0, stream>>>(
            P.bufA, P.bufBB, P.msg_b1 + (size_t)l * HID, P.Aw,
            P.bufP1, P.W2u + (size_t)l * HID * HID,
            P.mb2u + l * HID, P.rsum, P.upd_b1 + (size_t)l * HID,
            P.upd_W2 + (size_t)l * HID * HID, P.upd_b2 + (size_t)l * HID,
            hu[l - 1], sP, qP, lgp, lbp,
            (float*)hu[l], P.sts + l * 2048, P.sts + l * 2048 + 1024,
            (l == 2) ? P.gacc : nullptr);
    }

    // 9. qkv (LN-on-load with layer-2 stats)
    gemm3_kernel<<<dim3(192), 256, 0, stream>>>(
        hu[2], P.sts + 2 * 2048, P.sts + 2 * 2048 + 1024,
        P.ln_g + 2 * HID, P.ln_b + 2 * HID,
        P.Wq, P.Wk, P.Wv, P.bq, P.bk, P.bv,
        P.bufA, P.bufBB, P.bufU1);

    // 10. attention + mean (atomic into gacc)
    attention_kernel<<<dim3(256), 256, 0, stream>>>(P.bufA, P.bufBB, P.bufU1, P.gacc);

    // 11. fused tail
    tailf_kernel<<<dim3(8), 256, 0, stream>>>(P);
}

// Round 7
// 274.495 us; speedup vs baseline: 4.0337x; 1.0425x over previous
//
#include <hip/hip_runtime.h>
#include <math.h>

// Problem dims (fixed)
constexpr int NB  = 8;    // batch
constexpr int NR  = 128;  // rule nodes
constexpr int HID = 256;  // hidden
constexpr int NIN = 512;  // input dim
constexpr int DHD = 64;   // head dim
constexpr size_t SZ = (size_t)NB * NR * HID;  // 262144

struct KP {
    const float *x, *We, *be, *msg_W1, *msg_b1, *msg_W2, *msg_b2;
    const float *upd_W1, *upd_b1, *upd_W2, *upd_b2, *ln_g, *ln_b, *rule_adj;
    const float *Wq, *bq, *Wk, *bk, *Wv, *bv, *Wo, *bo, *ro_W1, *ro_b1, *ro_W2, *ro_b2;
    float* out;
    float *hu0, *hu1, *hu2;          // residual streams (pre-LN)
    float *bufA, *bufBB, *bufP1, *bufU1;
    float *W2u, *mb2u, *Aw, *rsum;   // W2u[l] = msg_W2[l]@upd_W1b[l], 3 mats
    float *mW1s;                     // layer0: msg_W1a + msg_W1b  [256,256]
    float *h0g, *c0g, *c1g;
    float *gacc;                     // tail mean accumulator [8,256]
    float *sts;                      // [3][2][1024]: sum, sumsq per layer
    float *scratch;
};

// ---------------------------------------------------------------------------
// 64x64-tile fp32 GEMM core (K=256, BK=16) — used only in setup (W2u).
// ---------------------------------------------------------------------------
__device__ __forceinline__ void gemm_core(
    float (&As)[16][68], float (&Bs)[16][64], int m0, int n0,
    const float* __restrict__ A, const float* __restrict__ B,
    float (&acc)[4][4])
{
    int tid = threadIdx.x;
    int ty = tid >> 4, tx = tid & 15;
    int arow = tid >> 2, acol = (tid & 3) << 2;
    int brow = tid >> 4, bcol = (tid & 15) << 2;
    int m = m0 + arow;

    auto loadA = [&](int k0) -> float4 {
        return *(const float4*)&A[(size_t)m * HID + k0 + acol];
    };

    float4 av = loadA(0);
    float4 bv = *(const float4*)&B[(size_t)brow * HID + n0 + bcol];

    for (int k0 = 0; k0 < HID; k0 += 16) {
        As[acol + 0][arow] = av.x;
        As[acol + 1][arow] = av.y;
        As[acol + 2][arow] = av.z;
        As[acol + 3][arow] = av.w;
        *(float4*)&Bs[brow][bcol] = bv;
        __syncthreads();
        if (k0 + 16 < HID) {
            av = loadA(k0 + 16);
            bv = *(const float4*)&B[(size_t)(k0 + 16 + brow) * HID + n0 + bcol];
        }
#pragma unroll
        for (int kk = 0; kk < 16; ++kk) {
            float4 af = *(const float4*)&As[kk][ty << 2];
            float4 bf = *(const float4*)&Bs[kk][tx << 2];
            float a_[4] = {af.x, af.y, af.z, af.w};
            float b_[4] = {bf.x, bf.y, bf.z, bf.w};
#pragma unroll
            for (int i = 0; i < 4; ++i)
#pragma unroll
                for (int j = 0; j < 4; ++j) acc[i][j] += a_[i] * b_[j];
        }
        __syncthreads();
    }
}

// ---------------------------------------------------------------------------
// Wave-split GEMV (tail): y[0..255] = act(xs @ W + bias). W row-major [256,256].
// ---------------------------------------------------------------------------
__device__ __forceinline__ void gemv256w(
    const float* xs, const float* __restrict__ W,
    const float* __restrict__ bias, int relu, float* ys, float* red)
{
    int tid = threadIdx.x;
    int w = tid >> 6, l = tid & 63;
    float4 acc = {0.f, 0.f, 0.f, 0.f};
    const float* Wp = W + (size_t)(w * 64) * HID + l * 4;
    const float* xp = xs + w * 64;
#pragma unroll 16
    for (int kk = 0; kk < 64; ++kk) {
        float xv = xp[kk];
        float4 wv = *(const float4*)(Wp + (size_t)kk * HID);
        acc.x += xv * wv.x; acc.y += xv * wv.y;
        acc.z += xv * wv.z; acc.w += xv * wv.w;
    }
    *(float4*)&red[w * 256 + l * 4] = acc;
    __syncthreads();
    float v = red[tid] + red[256 + tid] + red[512 + tid] + red[768 + tid];
    if (bias) v += bias[tid];
    if (relu) v = fmaxf(v, 0.0f);
    ys[tid] = v;
    __syncthreads();
}

// ---------------------------------------------------------------------------
// Setup: adjacency | W2u[l]=mW2[l]@uW1b[l] | mb2u | h0 | mW1s | prefetch.
// ---------------------------------------------------------------------------
__global__ __launch_bounds__(256) void setup0_kernel(KP P) {
    __shared__ union {
        struct { float As[16][68]; float Bs[16][64]; } g;
        struct { float xs[NIN]; float part[8][32]; } e;
    } L;
    int blk = blockIdx.x;
    int t = threadIdx.x;

    if (blk < 32) {
        // adjacency: 4 rows per block
        int rr = blk * 4 + (t >> 6);
        int l = t & 63;
        float s_loc = 0.f;
#pragma unroll
        for (int rep = 0; rep < 2; ++rep) {
            int j = l + rep * 64;
            float xv = P.rule_adj[rr * NR + j];
            float sg = 1.0f / (1.0f + expf(-xv));
            if (j == rr) sg = 0.0f;
            P.Aw[rr * NR + j] = sg;
            s_loc += sg;
        }
#pragma unroll
        for (int off = 32; off; off >>= 1) s_loc += __shfl_xor(s_loc, off);
        if (l == 0) P.rsum[rr] = s_loc;
    } else if (blk < 80) {
        // W2u[l2] = msg_W2[l2] @ upd_W1b[l2], l2 = 0..2
        int idx = blk - 32, l2 = idx >> 4, t16 = idx & 15;
        int m0 = (t16 >> 2) * 64, n0 = (t16 & 3) * 64;
        float acc[4][4] = {};
        gemm_core(L.g.As, L.g.Bs, m0, n0,
                  P.msg_W2 + (size_t)l2 * HID * HID,
                  P.upd_W1 + (size_t)l2 * 2 * HID * HID + (size_t)HID * HID,
                  acc);
        int ty = t >> 4, tx = t & 15;
        float* C = P.W2u + (size_t)l2 * HID * HID;
#pragma unroll
        for (int i = 0; i < 4; ++i) {
            int m = m0 + (ty << 2) + i, n = n0 + (tx << 2);
            float4 o = {acc[i][0], acc[i][1], acc[i][2], acc[i][3]};
            *(float4*)&C[(size_t)m * HID + n] = o;
        }
    } else if (blk < 83) {
        int l2 = blk - 80;
        const float* b2v = P.msg_b2 + l2 * HID;
        const float* Bm = P.upd_W1 + (size_t)l2 * 2 * HID * HID + (size_t)HID * HID;
        float acc = 0.f;
#pragma unroll 4
        for (int k = 0; k < HID; ++k) acc += b2v[k] * Bm[(size_t)k * HID + t];
        P.mb2u[l2 * HID + t] = acc;
    } else if (blk < 147) {
        // headE: h0[b] = x[b]@We + be, distributed (8 b x 8 col-slices)
        int idx = blk - 83;
        int b = idx >> 3, s = idx & 7;
        L.e.xs[t]       = P.x[b * NIN + t];
        L.e.xs[256 + t] = P.x[b * NIN + 256 + t];
        __syncthreads();
        int c = t & 31, seg = t >> 5;
        int col = s * 32 + c;
        const float* Wp = P.We + (size_t)(seg * 64) * HID + col;
        const float* xp = L.e.xs + seg * 64;
        float acc = 0.f;
#pragma unroll 16
        for (int k = 0; k < 64; ++k) acc += xp[k] * Wp[(size_t)k * HID];
        L.e.part[seg][c] = acc;
        __syncthreads();
        if (t < 32) {
            float v = 0.f;
#pragma unroll
            for (int sg = 0; sg < 8; ++sg) v += L.e.part[sg][t];
            int cc = s * 32 + t;
            P.h0g[b * HID + cc] = v + P.be[cc];
        }
    } else if (blk < 163) {
        // mW1s = msg_W1a[l0] + msg_W1b[l0]  (65536 floats, 16 blocks)
        int base = (blk - 147) * 4096;
        for (int i = t; i < 4096; i += 256) {
            int o = base + i;
            P.mW1s[o] = P.msg_W1[o] + P.msg_W1[65536 + o];
        }
    } else {
        // prefetch all weights -> warm L3 (poison evicts it every replay)
        int pfid = blk - 163, npf = 256 - 163;
        const float* arr[11] = {P.We, P.msg_W1, P.msg_W2, P.upd_W1, P.upd_W2,
                                P.Wq, P.Wk, P.Wv, P.Wo, P.ro_W1, P.ro_W2};
        const int n4[11] = {32768, 98304, 49152, 98304, 49152,
                            16384, 16384, 16384, 16384, 16384, 8192};
        float s = 0.f;
        for (int a = 0; a < 11; ++a) {
            const float4* p4 = (const float4*)arr[a];
            for (int i = pfid * 256 + t; i < n4[a]; i += npf * 256) {
                float4 v = p4[i];
                s += v.x + v.y + v.z + v.w;
            }
        }
        if (s == 1.0e37f) P.scratch[pfid] = s;  // keeps loads live
    }
}

// ---------------------------------------------------------------------------
// Head chain in one dispatch (grid 128):
//  z=0 (64 blocks, (b,s)): c0[b, s*32..+31] = h0[b] @ uW1a slice
//  z=1 (64 blocks, (b,s)): p0[b] = relu(h0[b]@mW1s + mb1) (full, redundant);
//                          c1[b, s*32..+31] = p0 @ W2u0 slice + mb2u0
// ---------------------------------------------------------------------------
__global__ __launch_bounds__(256) void headc_kernel(KP P) {
    __shared__ float h0s[HID];
    __shared__ float p0s[HID];
    __shared__ float part[8][32];
    int blk = blockIdx.x;
    int z = blk >> 6, bs = blk & 63;
    int b = bs >> 3, s = bs & 7;
    int t = threadIdx.x;
    h0s[t] = P.h0g[b * HID + t];
    __syncthreads();
    const float* Wslice;
    const float* xs;
    if (z == 0) {
        Wslice = P.upd_W1;   // uW1a (layer 0)
        xs = h0s;
    } else {
        float accp = 0.f;
#pragma unroll 8
        for (int k = 0; k < HID; ++k)
            accp += h0s[k] * P.mW1s[(size_t)k * HID + t];
        p0s[t] = fmaxf(accp + P.msg_b1[t], 0.0f);
        __syncthreads();
        Wslice = P.W2u;      // layer-0 W2u
        xs = p0s;
    }
    int c = t & 31, seg = t >> 5;
    int col = s * 32 + c;
    const float* Wp = Wslice + (size_t)(seg * 32) * HID + col;
    const float* xp = xs + seg * 32;
    float acc = 0.f;
#pragma unroll 8
    for (int k = 0; k < 32; ++k) acc += xp[k] * Wp[(size_t)k * HID];
    part[seg][c] = acc;
    __syncthreads();
    if (t < 32) {
        float v = 0.f;
#pragma unroll
        for (int sg = 0; sg < 8; ++sg) v += part[sg][t];
        int cc = s * 32 + t;
        if (z == 0) P.c0g[b * HID + cc] = v;
        else        P.c1g[b * HID + cc] = v + P.mb2u[cc];
    }
}

// ---------------------------------------------------------------------------
// rows4 @ W: out[ii] = rows[ii][:] dot W[:,n], n = threadIdx.x. W [256,256].
// ---------------------------------------------------------------------------
__device__ __forceinline__ void rows4_matmul(
    const float (&rows)[4][HID], const float* __restrict__ W, int n, float o[4])
{
    o[0] = o[1] = o[2] = o[3] = 0.f;
#pragma unroll 4
    for (int k0 = 0; k0 < HID; k0 += 4) {
        float w0 = W[(size_t)(k0 + 0) * HID + n];
        float w1 = W[(size_t)(k0 + 1) * HID + n];
        float w2 = W[(size_t)(k0 + 2) * HID + n];
        float w3 = W[(size_t)(k0 + 3) * HID + n];
#pragma unroll
        for (int ii = 0; ii < 4; ++ii) {
            float4 rv = *(const float4*)&rows[ii][k0];
            o[ii] += rv.x * w0 + rv.y * w1 + rv.z * w2 + rv.w * w3;
        }
    }
}

// Block-local row stats: thread holds v[ii] for rows m0+ii at its column.
__device__ __forceinline__ void row_stats4(
    float (&sred)[4][4][2], const float v[4], float* sts, float* stq, int m0)
{
    int w = threadIdx.x >> 6, l = threadIdx.x & 63;
    float s[4], q[4];
#pragma unroll
    for (int ii = 0; ii < 4; ++ii) { s[ii] = v[ii]; q[ii] = v[ii] * v[ii]; }
#pragma unroll
    for (int off = 32; off; off >>= 1) {
#pragma unroll
        for (int ii = 0; ii < 4; ++ii) {
            s[ii] += __shfl_xor(s[ii], off);
            q[ii] += __shfl_xor(q[ii], off);
        }
    }
    if (l == 0) {
#pragma unroll
        for (int ii = 0; ii < 4; ++ii) { sred[w][ii][0] = s[ii]; sred[w][ii][1] = q[ii]; }
    }
    __syncthreads();
    if (threadIdx.x < 8) {
        int row = threadIdx.x >> 1, isq = threadIdx.x & 1;
        float tot = sred[0][row][isq] + sred[1][row][isq] +
                    sred[2][row][isq] + sred[3][row][isq];
        (isq ? stq : sts)[m0 + row] = tot;
    }
}

// ---------------------------------------------------------------------------
// Layer 0 (collapsed): per block 4 rows.
// ---------------------------------------------------------------------------
__global__ __launch_bounds__(256) void layer0r_kernel(KP P) {
    __shared__ float u1s[4][HID];
    __shared__ float sred[4][4][2];
    int blk = blockIdx.x;
    int m0 = blk * 4;
    int b = m0 >> 7, i0 = m0 & 127;
    int t = threadIdx.x;

    float c0v = P.c0g[b * HID + t];
    float c1v = P.c1g[b * HID + t];
    float ubv = P.upd_b1[t];
#pragma unroll
    for (int ii = 0; ii < 4; ++ii)
        u1s[ii][t] = fmaxf(c0v + P.rsum[i0 + ii] * c1v + ubv, 0.0f);
    __syncthreads();

    float u[4];
    rows4_matmul(u1s, P.upd_W2, t, u);

    float h0v = P.h0g[b * HID + t] + P.upd_b2[t];
    float v[4];
#pragma unroll
    for (int ii = 0; ii < 4; ++ii) {
        v[ii] = u[ii] + h0v;
        P.hu0[(size_t)(m0 + ii) * HID + t] = v[ii];
    }
    __syncthreads();
    row_stats4(sred, v, P.sts, P.sts + 1024, m0);
}

// ---------------------------------------------------------------------------
// Triple GEMM, LN-on-load A. 32x64 tiles, K=256, BK=32. grid 384.
// z = blk>>7, tile = blk&127: m0 = (tile>>2)*32, n0 = (tile&3)*64.
// ---------------------------------------------------------------------------
__global__ __launch_bounds__(256) void gemm3_kernel(
    const float* __restrict__ A, const float* __restrict__ ssum, const float* __restrict__ ssq,
    const float* __restrict__ lng, const float* __restrict__ lnb,
    const float* __restrict__ B0, const float* __restrict__ B1, const float* __restrict__ B2,
    const float* __restrict__ bias0, const float* __restrict__ bias1, const float* __restrict__ bias2,
    float* __restrict__ C0, float* __restrict__ C1, float* __restrict__ C2)
{
    __shared__ float As[32][36];   // [k][row], padded
    __shared__ float Bs[32][64];
    int blk = blockIdx.x;
    int z = blk >> 7, tile = blk & 127;
    const float* B    = (z == 0) ? B0 : (z == 1) ? B1 : B2;
    const float* bias = (z == 0) ? bias0 : (z == 1) ? bias1 : bias2;
    float* C          = (z == 0) ? C0 : (z == 1) ? C1 : C2;
    int m0 = (tile >> 2) * 32, n0 = (tile & 3) * 64;

    int tid = threadIdx.x;
    int ar = tid >> 3;                 // 32 rows
    int acol = (tid & 7) << 2;         // 32 k / step
    int brow = tid >> 4;               // 16 (+16)
    int bcol = (tid & 15) << 2;
    int m = m0 + ar;

    bool ln = (ssum != nullptr);
    float mu = 0.f, inv = 1.f;
    if (ln) {
        float s = ssum[m], q = ssq[m];
        mu = s * (1.0f / HID);
        inv = rsqrtf(q * (1.0f / HID) - mu * mu + 1e-5f);
    }
    auto loadA = [&](int k0) -> float4 {
        int kx = k0 + acol;
        float4 v = *(const float4*)&A[(size_t)m * HID + kx];
        if (ln) {
            float4 g = *(const float4*)(lng + kx);
            float4 b = *(const float4*)(lnb + kx);
            v.x = (v.x - mu) * inv * g.x + b.x;
            v.y = (v.y - mu) * inv * g.y + b.y;
            v.z = (v.z - mu) * inv * g.z + b.z;
            v.w = (v.w - mu) * inv * g.w + b.w;
        }
        return v;
    };

    float acc[2][4] = {};
    float4 av  = loadA(0);
    float4 bv0 = *(const float4*)&B[(size_t)brow * HID + n0 + bcol];
    float4 bv1 = *(const float4*)&B[(size_t)(16 + brow) * HID + n0 + bcol];

    int ty = tid >> 4, tx = tid & 15;
    int r0 = ty << 1;

    for (int k0 = 0; k0 < HID; k0 += 32) {
        As[acol + 0][ar] = av.x;
        As[acol + 1][ar] = av.y;
        As[acol + 2][ar] = av.z;
        As[acol + 3][ar] = av.w;
        *(float4*)&Bs[brow][bcol]      = bv0;
        *(float4*)&Bs[brow + 16][bcol] = bv1;
        __syncthreads();
        if (k0 + 32 < HID) {
            av  = loadA(k0 + 32);
            bv0 = *(const float4*)&B[(size_t)(k0 + 32 + brow) * HID + n0 + bcol];
            bv1 = *(const float4*)&B[(size_t)(k0 + 48 + brow) * HID + n0 + bcol];
        }
#pragma unroll
        for (int kk = 0; kk < 32; ++kk) {
            float a0 = As[kk][r0];
            float a1 = As[kk][r0 + 1];
            float4 bf = *(const float4*)&Bs[kk][tx << 2];
            acc[0][0] += a0 * bf.x; acc[0][1] += a0 * bf.y;
            acc[0][2] += a0 * bf.z; acc[0][3] += a0 * bf.w;
            acc[1][0] += a1 * bf.x; acc[1][1] += a1 * bf.y;
            acc[1][2] += a1 * bf.z; acc[1][3] += a1 * bf.w;
        }
        __syncthreads();
    }

#pragma unroll
    for (int i = 0; i < 2; ++i) {
        int mm = m0 + r0 + i, n = n0 + (tx << 2);
        float4 o = {acc[i][0], acc[i][1], acc[i][2], acc[i][3]};
        if (bias) {
            float4 bb = *(const float4*)&bias[n];
            o.x += bb.x; o.y += bb.y; o.z += bb.z; o.w += bb.w;
        }
        *(float4*)&C[(size_t)mm * HID + n] = o;
    }
}

// ---------------------------------------------------------------------------
// Fused aggregate + u1 + resid GEMM + LN stats. Per block: 4 complete rows.
// ---------------------------------------------------------------------------
__global__ __launch_bounds__(256) void agg_u1r_kernel(
    const float* __restrict__ a, const float* __restrict__ bbv,
    const float* __restrict__ mb1, const float* __restrict__ Aw,
    const float* __restrict__ P1, const float* __restrict__ W2u,
    const float* __restrict__ mb2u, const float* __restrict__ rsum,
    const float* __restrict__ ub1,
    const float* __restrict__ uW2, const float* __restrict__ ub2,
    const float* __restrict__ huprev, const float* __restrict__ sP, const float* __restrict__ qP,
    const float* __restrict__ lngp, const float* __restrict__ lnbp,
    float* __restrict__ hunew, float* __restrict__ sN, float* __restrict__ qN,
    float* __restrict__ gzero)
{
    __shared__ float ap[4][HID];
    __shared__ float u1s[4][HID];
    __shared__ float sred[4][4][2];
    int blk = blockIdx.x;
    int b  = blk >> 5;
    int i0 = (blk & 31) * 4;
    int m0 = b * NR + i0;
    int t  = threadIdx.x;

    if (gzero && blk == 0) {
#pragma unroll
        for (int i = 0; i < 8; ++i) gzero[i * 256 + t] = 0.f;
    }

    // aggregate
    float bias = mb1[t];
    float ai[4], acc[4] = {0.f, 0.f, 0.f, 0.f};
#pragma unroll
    for (int ii = 0; ii < 4; ++ii)
        ai[ii] = a[(size_t)(m0 + ii) * HID + t] + bias;
    const float* bbb = &bbv[(size_t)b * NR * HID + t];
#pragma unroll 4
    for (int j = 0; j < NR; ++j) {
        float bj = bbb[(size_t)j * HID];
#pragma unroll
        for (int ii = 0; ii < 4; ++ii) {
            float pre = fmaxf(ai[ii] + bj, 0.0f);
            acc[ii] += Aw[(i0 + ii) * NR + j] * pre;
        }
    }
#pragma unroll
    for (int ii = 0; ii < 4; ++ii) ap[ii][t] = acc[ii];
    __syncthreads();

    // u1 = relu(aggpre@W2u + P1 + rsum*mb2u + ub1)
    float w2[4];
    rows4_matmul(ap, W2u, t, w2);
    float mbv = mb2u[t], ubv = ub1[t];
#pragma unroll
    for (int ii = 0; ii < 4; ++ii) {
        float vv = w2[ii] + P1[(size_t)(m0 + ii) * HID + t] + rsum[i0 + ii] * mbv + ubv;
        u1s[ii][t] = fmaxf(vv, 0.0f);
    }
    __syncthreads();

    // u = u1@uW2 ; hu_new = LN_prev(huprev) + u + ub2
    float u[4];
    rows4_matmul(u1s, uW2, t, u);

    float gv = lngp[t], btv = lnbp[t], ub2v = ub2[t];
    float v[4];
#pragma unroll
    for (int ii = 0; ii < 4; ++ii) {
        int m = m0 + ii;
        float sp = sP[m], qp = qP[m];
        float mup = sp * (1.0f / HID);
        float invp = rsqrtf(qp * (1.0f / HID) - mup * mup + 1e-5f);
        float hp = huprev[(size_t)m * HID + t];
        v[ii] = (hp - mup) * invp * gv + btv + u[ii] + ub2v;
        hunew[(size_t)m * HID + t] = v[ii];
    }
    __syncthreads();
    row_stats4(sred, v, sN, qN, m0);
}

// ---------------------------------------------------------------------------
// Fused attention + mean: blk = bh*8 + ig; 16 q-rows per block, one (b,head).
// ---------------------------------------------------------------------------
__global__ __launch_bounds__(256) void attention_kernel(
    const float* __restrict__ q, const float* __restrict__ k,
    const float* __restrict__ v, float* __restrict__ gacc)
{
    __shared__ struct { float KhT[64][128]; float S[16][128]; float qs[16][64]; } L;
    int blk = blockIdx.x;
    int bh = blk >> 3, ig = blk & 7;
    int b = bh >> 2, hd = bh & 3;
    int i0 = ig * 16;
    int t = threadIdx.x;
    const float* qg = q + ((size_t)b * NR) * HID + hd * DHD;
    const float* kg = k + ((size_t)b * NR) * HID + hd * DHD;
    const float* vg = v + ((size_t)b * NR) * HID + hd * DHD;

    {   // stage K^T
        int j = t >> 1, half = t & 1;
        const float* krow = kg + (size_t)j * HID + half * 32;
#pragma unroll
        for (int c = 0; c < 32; c += 4) {
            float4 kv = *(const float4*)(krow + c);
            L.KhT[half * 32 + c + 0][j] = kv.x;
            L.KhT[half * 32 + c + 1][j] = kv.y;
            L.KhT[half * 32 + c + 2][j] = kv.z;
            L.KhT[half * 32 + c + 3][j] = kv.w;
        }
    }
    {   // stage q rows
        int ii = t >> 4, d0 = (t & 15) * 4;
        *(float4*)&L.qs[ii][d0] = *(const float4*)(qg + (size_t)(i0 + ii) * HID + d0);
    }
    __syncthreads();
    {   // scores
        int j = t & 127, ii2 = t >> 7;
        float acc[8] = {0.f,0.f,0.f,0.f,0.f,0.f,0.f,0.f};
#pragma unroll 4
        for (int d = 0; d < 64; ++d) {
            float kv = L.KhT[d][j];
#pragma unroll
            for (int ii = 0; ii < 8; ++ii) acc[ii] += L.qs[ii2 * 8 + ii][d] * kv;
        }
#pragma unroll
        for (int ii = 0; ii < 8; ++ii) L.S[ii2 * 8 + ii][j] = acc[ii] * 0.125f;
    }
    __syncthreads();
    {   // softmax per row
        int w = t >> 6, l = t & 63;
#pragma unroll
        for (int r = w * 4; r < w * 4 + 4; ++r) {
            float e0 = L.S[r][l], e1 = L.S[r][l + 64];
            float mx = fmaxf(e0, e1);
#pragma unroll
            for (int off = 32; off; off >>= 1) mx = fmaxf(mx, __shfl_xor(mx, off));
            e0 = expf(e0 - mx); e1 = expf(e1 - mx);
            float sm = e0 + e1;
#pragma unroll
            for (int off = 32; off; off >>= 1) sm += __shfl_xor(sm, off);
            float inv = 1.0f / sm;
            L.S[r][l] = e0 * inv; L.S[r][l + 64] = e1 * inv;
        }
    }
    __syncthreads();
    {   // PV + row-sum into gacc
        int d = t & 63, ir = t >> 6;
        float accv[4] = {0.f, 0.f, 0.f, 0.f};
        const float* vp = vg + d;
#pragma unroll 8
        for (int j = 0; j < NR; ++j) {
            float vv = vp[(size_t)j * HID];
#pragma unroll
            for (int p = 0; p < 4; ++p) accv[p] += L.S[p * 4 + ir][j] * vv;
        }
        float s = accv[0] + accv[1] + accv[2] + accv[3];
        atomicAdd(&gacc[b * HID + hd * DHD + d], s);
    }
}

// ---------------------------------------------------------------------------
// Fused tail: per-batch chain. 8 blocks.
// ---------------------------------------------------------------------------
__global__ __launch_bounds__(256) void tailf_kernel(KP P) {
    __shared__ float v0[HID], v1[HID], v2[HID];
    __shared__ float red[1024];
    int b = blockIdx.x;
    int t = threadIdx.x;
    int w = t >> 6, l = t & 63;

    v0[t] = P.gacc[b * HID + t] * (1.0f / NR);
    __syncthreads();
    gemv256w(v0, P.Wo, P.bo, 0, v1, red);
    gemv256w(v1, P.ro_W1, P.ro_b1, 1, v2, red);

    {   // logits: N=128; lane l -> outputs 2l,2l+1; wave w -> K quarter
        float2 acc = {0.f, 0.f};
        const float* Wp = P.ro_W2 + (size_t)(w * 64) * NR + l * 2;
        const float* xp = v2 + w * 64;
#pragma unroll 8
        for (int kk = 0; kk < 64; ++kk) {
            float xv = xp[kk];
            float2 wv = *(const float2*)(Wp + (size_t)kk * NR);
            acc.x += xv * wv.x; acc.y += xv * wv.y;
        }
        *(float2*)&red[w * 128 + l * 2] = acc;
        __syncthreads();
    }
    float logit = -1e30f;
    if (t < NR) logit = red[t] + red[128 + t] + red[256 + t] + red[384 + t] + P.ro_b2[t];
    __syncthreads();
    float m = logit;
#pragma unroll
    for (int off = 32; off; off >>= 1) m = fmaxf(m, __shfl_xor(m, off));
    if (l == 0) red[w] = m;
    __syncthreads();
    m = fmaxf(red[0], red[1]);
    float e = (t < NR) ? expf(logit - m) : 0.0f;
    float ssum = e;
#pragma unroll
    for (int off = 32; off; off >>= 1) ssum += __shfl_xor(ssum, off);
    if (l == 0) red[4 + w] = ssum;
    __syncthreads();
    float tot = red[4] + red[5];
    if (t < NR) P.out[b * NR + t] = e / tot;
}

// ---------------------------------------------------------------------------
extern "C" void kernel_launch(void* const* d_in, const int* in_sizes, int n_in,
                              void* d_out, int out_size, void* d_ws, size_t ws_size,
                              hipStream_t stream)
{
    KP P;
    P.x        = (const float*)d_in[0];
    P.We       = (const float*)d_in[1];
    P.be       = (const float*)d_in[2];
    P.msg_W1   = (const float*)d_in[3];
    P.msg_b1   = (const float*)d_in[4];
    P.msg_W2   = (const float*)d_in[5];
    P.msg_b2   = (const float*)d_in[6];
    P.upd_W1   = (const float*)d_in[7];
    P.upd_b1   = (const float*)d_in[8];
    P.upd_W2   = (const float*)d_in[9];
    P.upd_b2   = (const float*)d_in[10];
    P.ln_g     = (const float*)d_in[11];
    P.ln_b     = (const float*)d_in[12];
    P.rule_adj = (const float*)d_in[13];
    P.Wq       = (const float*)d_in[14];
    P.bq       = (const float*)d_in[15];
    P.Wk       = (const float*)d_in[16];
    P.bk       = (const float*)d_in[17];
    P.Wv       = (const float*)d_in[18];
    P.bv       = (const float*)d_in[19];
    P.Wo       = (const float*)d_in[20];
    P.bo       = (const float*)d_in[21];
    P.ro_W1    = (const float*)d_in[22];
    P.ro_b1    = (const float*)d_in[23];
    P.ro_W2    = (const float*)d_in[24];
    P.ro_b2    = (const float*)d_in[25];
    P.out      = (float*)d_out;

    float* b0 = (float*)d_ws;
    P.hu0    = b0;  b0 += SZ;
    P.hu1    = b0;  b0 += SZ;
    P.hu2    = b0;  b0 += SZ;
    P.bufA   = b0;  b0 += SZ;
    P.bufBB  = b0;  b0 += SZ;
    P.bufP1  = b0;  b0 += SZ;
    P.bufU1  = b0;  b0 += SZ;
    P.W2u    = b0;  b0 += 3 * HID * HID;
    P.mb2u   = b0;  b0 += 3 * HID;
    P.mW1s   = b0;  b0 += HID * HID;
    P.Aw     = b0;  b0 += NR * NR;
    P.rsum   = b0;  b0 += NR;
    P.h0g    = b0;  b0 += NB * HID;
    P.c0g    = b0;  b0 += NB * HID;
    P.c1g    = b0;  b0 += NB * HID;
    P.gacc   = b0;  b0 += NB * HID;
    P.sts    = b0;  b0 += 3 * 2048;
    P.scratch= b0;  b0 += 256;

    const float* hu[3] = {P.hu0, P.hu1, P.hu2};

    // 1. setup: adj | W2u (3 layers) | mb2u | h0 | mW1s | prefetch
    setup0_kernel<<<dim3(256), 256, 0, stream>>>(P);

    // 2. head chain fused: c0 || (p0 -> c1)
    headc_kernel<<<dim3(128), 256, 0, stream>>>(P);

    // 3. layer 0 (collapsed) -> hu0, sts0
    layer0r_kernel<<<dim3(256), 256, 0, stream>>>(P);

    // 4-7. layers 1..2
    for (int l = 1; l < 3; ++l) {
        const float* mW1 = P.msg_W1 + (size_t)l * 2 * HID * HID;
        const float* sP  = P.sts + (l - 1) * 2048;
        const float* qP  = sP + 1024;
        const float* lgp = P.ln_g + (size_t)(l - 1) * HID;
        const float* lbp = P.ln_b + (size_t)(l - 1) * HID;

        gemm3_kernel<<<dim3(384), 256, 0, stream>>>(
            hu[l - 1], sP, qP, lgp, lbp,
            mW1, mW1 + (size_t)HID * HID, P.upd_W1 + (size_t)l * 2 * HID * HID,
            nullptr, nullptr, nullptr,
            P.bufA, P.bufBB, P.bufP1);

        agg_u1r_kernel<<<dim3(256), 256, 0, stream>>>(
            P.bufA, P.bufBB, P.msg_b1 + (size_t)l * HID, P.Aw,
            P.bufP1, P.W2u + (size_t)l * HID * HID,
            P.mb2u + l * HID, P.rsum, P.upd_b1 + (size_t)l * HID,
            P.upd_W2 + (size_t)l * HID * HID, P.upd_b2 + (size_t)l * HID,
            hu[l - 1], sP, qP, lgp, lbp,
            (float*)hu[l], P.sts + l * 2048, P.sts + l * 2048 + 1024,
            (l == 2) ? P.gacc : nullptr);
    }

    // 8. qkv (LN-on-load with layer-2 stats)
    gemm3_kernel<<<dim3(384), 256, 0, stream>>>(
        hu[2], P.sts + 2 * 2048, P.sts + 2 * 2048 + 1024,
        P.ln_g + 2 * HID, P.ln_b + 2 * HID,
        P.Wq, P.Wk, P.Wv, P.bq, P.bk, P.bv,
        P.bufA, P.bufBB, P.bufU1);

    // 9. attention + mean (atomic into gacc)
    attention_kernel<<<dim3(256), 256, 0, stream>>>(P.bufA, P.bufBB, P.bufU1, P.gacc);

    // 10. fused tail
    tailf_kernel<<<dim3(8), 256, 0, stream>>>(P);
}